// Round 14
// baseline (312.533 us; speedup 1.0000x reference)
//
#include <hip/hip_runtime.h>
#include <cstdint>
#include <cstddef>

#define DEVI __device__ __forceinline__

typedef __attribute__((ext_vector_type(8))) short s16x8;
typedef __attribute__((ext_vector_type(8))) unsigned short u16x8;
typedef __attribute__((ext_vector_type(4))) float f32x4;
typedef unsigned short u16;

static constexpr int Bc = 2, Tc = 2048, Hc = 16, DMc = 1024;
static constexpr int VTS = 2064;  // V^T row stride in u16 (4128B: non-pow2, 16B-aligned)

DEVI float bf2f(u16 u){ unsigned int x = ((unsigned int)u) << 16; return __builtin_bit_cast(float, x); }
DEVI u16 f2bf(float f){
  unsigned int u = __builtin_bit_cast(unsigned int, f);
  u += 0x7FFFu + ((u >> 16) & 1u);
  return (u16)(u >> 16);
}

DEVI float waveSum(float v){
  #pragma unroll
  for (int m = 1; m < 64; m <<= 1) v += __shfl_xor(v, m);
  return v;
}

DEVI void gload16(const void* g, void* l){
  __builtin_amdgcn_global_load_lds((const __attribute__((address_space(1))) void*)g,
                                   (__attribute__((address_space(3))) void*)l, 16, 0, 0);
}

// ---------------- fp32 -> bf16 convert ----------------
__global__ __launch_bounds__(256) void cvt_f32_bf16(const float* __restrict__ in,
                                                    u16* __restrict__ out, int n4){
  int i = blockIdx.x * blockDim.x + threadIdx.x;
  int stride = gridDim.x * blockDim.x;
  for (int idx = i; idx < n4; idx += stride){
    float4 v = ((const float4*)in)[idx];
    ushort4 o;
    o.x = f2bf(v.x); o.y = f2bf(v.y); o.z = f2bf(v.z); o.w = f2bf(v.w);
    ((ushort4*)out)[idx] = o;
  }
}

// ---------------- GEMM 256x256, BK=64, 8-phase counted-vmcnt pipeline ----------------
__global__ __launch_bounds__(512, 1) void gemm256_bt(
    const u16* __restrict__ A, int lda, const u16* __restrict__ W, int ldw,
    u16* __restrict__ outB, const float* __restrict__ bias,
    const float* __restrict__ scale, float smul,
    int M, int N, int K)
{
  __shared__ u16 lds8[65536];   // 128 KiB: A slots [0,32768), B slots [32768,65536)
  const int tid = threadIdx.x, lane = tid & 63, wave = tid >> 6;
  const int wm = wave >> 2, wn = wave & 3;
  const int g = lane >> 4, cl = lane & 15;
  // n-chunked XCD swizzle (gridDim.x % 8 == 0)
  const int F = blockIdx.y * gridDim.x + blockIdx.x;
  const int xcd = F & 7, i0 = F >> 3;
  const int NCH = gridDim.x >> 3;
  const int n0 = (xcd * NCH + i0 % NCH) * 256;
  const int m0 = (i0 / NCH) * 256;

  const int nt = K >> 6;         // K-tiles
  const int iters = nt >> 1;     // 2 K-tiles per iteration
  const int wuni = tid & ~63;

  f32x4 acc[8][4] = {};

  auto stageA = [&](int h, int t){
    char* dst = (char*)(lds8 + (size_t)(2 * (t & 1) + h) * 8192);
    const int k0 = t << 6;
    #pragma unroll
    for (int j = 0; j < 2; ++j){
      const int idx = j * 512 + tid;            // 0..1023: row=idx>>3, blk=idx&7
      const int row = idx >> 3;
      const int sb = ((idx & 7) ^ (row & 7)) << 3;
      gload16(A + (size_t)(m0 + h * 128 + row) * lda + k0 + sb,
              dst + ((j * 512 + wuni) << 4));
    }
  };
  auto stageB = [&](int h, int t){
    char* dst = (char*)(lds8 + 32768 + (size_t)(2 * (t & 1) + h) * 8192);
    const int k0 = t << 6;
    #pragma unroll
    for (int j = 0; j < 2; ++j){
      const int idx = j * 512 + tid;
      const int row = idx >> 3;
      const int sb = ((idx & 7) ^ (row & 7)) << 3;
      gload16(W + (size_t)(n0 + h * 128 + row) * ldw + k0 + sb,
              dst + ((j * 512 + wuni) << 4));
    }
  };

  // prologue: B(0), A(0), B(1) = 12 gloads
  stageB(0, 0); stageB(1, 0); stageA(0, 0); stageA(1, 0); stageB(0, 1); stageB(1, 1);

  s16x8 bF[4][2];
  for (int v = 0; v < iters; ++v){
    const bool lastIt = (v == iters - 1);
    #pragma unroll
    for (int p = 0; p < 8; ++p){
      const int tt = p >> 2, q = p & 3;
      const int t = 2 * v + tt;
      // stage schedule (slot legality: re-stage only after last read's barrier)
      if (p == 0)      stageA(0, 2 * v + 1);
      else if (p == 1) stageA(1, 2 * v + 1);
      else if (p == 2){ if (2 * v + 2 < nt) stageB(0, 2 * v + 2); }
      else if (p == 3){ if (2 * v + 2 < nt) stageB(1, 2 * v + 2); }
      else if (p == 4){ if (2 * v + 2 < nt) stageA(0, 2 * v + 2); }
      else if (p == 5){ if (2 * v + 2 < nt) stageA(1, 2 * v + 2); }
      else if (p == 6){ if (2 * v + 3 < nt) stageB(0, 2 * v + 3); }
      else            { if (2 * v + 3 < nt) stageB(1, 2 * v + 3); }

      if (p == 0) asm volatile("s_waitcnt vmcnt(6)" ::: "memory");
      if (p == 4){
        if (lastIt) asm volatile("s_waitcnt vmcnt(0)" ::: "memory");
        else        asm volatile("s_waitcnt vmcnt(6)" ::: "memory");
      }

      // ds_read register subtile
      const int abase = (2 * (t & 1) + wm) * 8192;
      s16x8 aF[2][2];
      #pragma unroll
      for (int i2 = 0; i2 < 2; ++i2){
        const int r = (2 * q + i2) * 16 + cl;
        #pragma unroll
        for (int kk = 0; kk < 2; ++kk)
          aF[i2][kk] = *(const s16x8*)&lds8[abase + r * 64 + (((kk * 4 + g) ^ (r & 7)) << 3)];
      }
      if (q == 0){
        const int bbase = 32768 + (2 * (t & 1) + (wn >> 1)) * 8192;
        #pragma unroll
        for (int j = 0; j < 4; ++j){
          const int rb2 = (wn & 1) * 64 + j * 16 + cl;
          #pragma unroll
          for (int kk = 0; kk < 2; ++kk)
            bF[j][kk] = *(const s16x8*)&lds8[bbase + rb2 * 64 + (((kk * 4 + g) ^ (rb2 & 7)) << 3)];
        }
      }

      asm volatile("s_barrier" ::: "memory");
      __builtin_amdgcn_s_setprio(1);
      #pragma unroll
      for (int i2 = 0; i2 < 2; ++i2)
        #pragma unroll
        for (int j = 0; j < 4; ++j)
          #pragma unroll
          for (int kk = 0; kk < 2; ++kk)
            acc[2 * q + i2][j] = __builtin_amdgcn_mfma_f32_16x16x32_bf16(
                aF[i2][kk], bF[j][kk], acc[2 * q + i2][j], 0, 0, 0);
      __builtin_amdgcn_s_setprio(0);
      asm volatile("s_barrier" ::: "memory");
    }
  }

  // epilogue
  const int rb = m0 + wm * 128 + (g << 2);
  const int cb = n0 + wn * 64 + cl;
  #pragma unroll
  for (int i = 0; i < 8; ++i){
    #pragma unroll
    for (int j = 0; j < 4; ++j){
      const int col = cb + j * 16;
      const float sc = scale[col] * smul;
      const float bi = bias[col];
      #pragma unroll
      for (int r = 0; r < 4; ++r){
        const int row = rb + i * 16 + r;
        outB[(size_t)row * N + col] = f2bf((acc[i][j][r] + bi) * sc);
      }
    }
  }
}

// ---------------- GEMM 128x128, BK=64, XOR-swizzled LDS (conflict-free) ----------------
// EPI 0: fp32 out (+ optional bias)
// EPI 1: bf16 out: Q,K -> qk[bh][t][128]; V -> transposed vt[bh][d][VTS]
template<int EPI>
__global__ __launch_bounds__(256) void gemm_bt(
    const u16* __restrict__ A, int lda, const u16* __restrict__ W,
    float* __restrict__ outF, u16* __restrict__ outB, u16* __restrict__ outB2,
    const float* __restrict__ bias, const float* __restrict__ scale, float smul,
    int M, int N, int K)
{
  __shared__ u16 lA[128 * 64];
  __shared__ u16 lB[128 * 64];
  const int tid = threadIdx.x, lane = tid & 63;
  const int wave = tid >> 6, wm = wave >> 1, wn = wave & 1;
  const int g = lane >> 4, cl = lane & 15;
  // n-chunked XCD swizzle (requires gridDim.x % 8 == 0; bijective)
  const int F = blockIdx.y * gridDim.x + blockIdx.x;
  const int xcd = F & 7, i0 = F >> 3;
  const int NCH = gridDim.x >> 3;
  const int n0 = (xcd * NCH + i0 % NCH) * 128;
  const int m0 = (i0 / NCH) * 128;
  f32x4 acc[4][4] = {};
  const int kT = K >> 6;
  char* lAc = (char*)lA;
  char* lBc = (char*)lB;
  const int wuni = (tid & ~63);

  for (int kt = 0; kt < kT; ++kt){
    const int k0 = kt << 6;
    __syncthreads();
    #pragma unroll
    for (int j = 0; j < 4; ++j){
      const int idx = j * 256 + tid;            // 0..1023: row=idx>>3, blk=idx&7
      const int row = idx >> 3;
      const int sb = ((idx & 7) ^ (row & 7)) << 3;  // pre-swizzled source col-block
      gload16(A + (size_t)(m0 + row) * lda + k0 + sb,
              lAc + ((j * 256 + wuni) << 4));
    }
    #pragma unroll
    for (int j = 0; j < 4; ++j){
      const int idx = j * 256 + tid;
      const int row = idx >> 3;
      const int sb = ((idx & 7) ^ (row & 7)) << 3;
      gload16(W + (size_t)(n0 + row) * K + k0 + sb,
              lBc + ((j * 256 + wuni) << 4));
    }
    __syncthreads();

    #pragma unroll
    for (int kk = 0; kk < 2; ++kk){
      s16x8 aF[4], bF[4];
      #pragma unroll
      for (int i = 0; i < 4; ++i){
        const int ra = wm * 64 + i * 16 + cl;
        aF[i] = *(const s16x8*)&lA[ra * 64 + (((kk * 4 + g) ^ (ra & 7)) << 3)];
      }
      #pragma unroll
      for (int j = 0; j < 4; ++j){
        const int rbr = wn * 64 + j * 16 + cl;
        bF[j] = *(const s16x8*)&lB[rbr * 64 + (((kk * 4 + g) ^ (rbr & 7)) << 3)];
      }
      #pragma unroll
      for (int i = 0; i < 4; ++i)
        #pragma unroll
        for (int j = 0; j < 4; ++j)
          acc[i][j] = __builtin_amdgcn_mfma_f32_16x16x32_bf16(aF[i], bF[j], acc[i][j], 0, 0, 0);
    }
  }

  const int rb = m0 + wm * 64 + (g << 2);
  const int cb = n0 + wn * 64 + cl;
  #pragma unroll
  for (int i = 0; i < 4; ++i){
    #pragma unroll
    for (int j = 0; j < 4; ++j){
      #pragma unroll
      for (int r = 0; r < 4; ++r){
        const int row = rb + i * 16 + r;
        const int col = cb + j * 16;
        float v = acc[i][j][r];
        if (EPI == 0){
          if (bias) v += bias[col];
          outF[(size_t)row * N + col] = v;
        } else if (EPI == 1){
          const int b = row >> 11;           // T = 2048
          const int t = row & (Tc - 1);
          const int h = col / 192;
          const int e = col - h * 192;
          const int bh = b * Hc + h;
          if (e < 128){
            outB[((size_t)bh * Tc + t) * 128 + e] = f2bf(v);         // Q|K packed
          } else {
            outB2[((size_t)bh * 64 + (e - 128)) * VTS + t] = f2bf(v); // V^T [d][VTS]
          }
        } else {
          v = (v + bias[col]) * (scale[col] * smul);
          outB[(size_t)row * N + col] = f2bf(v);
        }
      }
    }
  }
}

// ---------------- GEMM 64x64, BK=128, XOR-swizzled LDS (conflict-free) ----------------
__global__ __launch_bounds__(256) void gemm64_bt(
    const u16* __restrict__ A, int lda, const u16* __restrict__ W, int ldw,
    float* __restrict__ outF, const float* __restrict__ bias,
    int M, int N, int K)
{
  __shared__ u16 lA[64 * 128];
  __shared__ u16 lB[64 * 128];
  const int tid = threadIdx.x, lane = tid & 63;
  const int wave = tid >> 6, wm = wave >> 1, wn = wave & 1;
  const int g = lane >> 4, cl = lane & 15;
  // XCD-chunked bijective swizzle (nwg % 8 == 0)
  const int nwg = gridDim.x * gridDim.y;
  int flat = blockIdx.y * gridDim.x + blockIdx.x;
  flat = (flat & 7) * (nwg >> 3) + (flat >> 3);
  const int n0 = (flat % gridDim.x) * 64;
  const int m0 = (flat / gridDim.x) * 64;
  f32x4 acc[2][2] = {};
  const int kT = K >> 7;
  const int wuni = tid & ~63;

  for (int kt = 0; kt < kT; ++kt){
    const int k0 = kt << 7;
    __syncthreads();
    #pragma unroll
    for (int it = 0; it < 4; ++it){
      const int idx = it * 256 + tid;        // 0..1023: row=idx>>4, blk=idx&15 (16x 16B/row)
      const int row = idx >> 4, blk = idx & 15;
      const int sb = ((blk & 8) | ((blk & 7) ^ (row & 7))) << 3;  // swizzle within 128B halves
      gload16(A + (size_t)(m0 + row) * lda + k0 + sb,
              (char*)lA + ((it * 256 + wuni) << 4));
      gload16(W + (size_t)(n0 + row) * ldw + k0 + sb,
              (char*)lB + ((it * 256 + wuni) << 4));
    }
    __syncthreads();

    #pragma unroll
    for (int kk = 0; kk < 4; ++kk){
      s16x8 aF[2], bF[2];
      #pragma unroll
      for (int i = 0; i < 2; ++i){
        const int ra = wm * 32 + i * 16 + cl;
        const int ba = kk * 4 + g;
        const int sa = ((ba & 8) | ((ba & 7) ^ (ra & 7))) << 3;
        aF[i] = *(const s16x8*)&lA[ra * 128 + sa];
        const int rbr = wn * 32 + i * 16 + cl;
        const int sbw = ((ba & 8) | ((ba & 7) ^ (rbr & 7))) << 3;
        bF[i] = *(const s16x8*)&lB[rbr * 128 + sbw];
      }
      #pragma unroll
      for (int i = 0; i < 2; ++i)
        #pragma unroll
        for (int j = 0; j < 2; ++j)
          acc[i][j] = __builtin_amdgcn_mfma_f32_16x16x32_bf16(aF[i], bF[j], acc[i][j], 0, 0, 0);
    }
  }

  const int rb = m0 + wm * 32 + (g << 2);
  const int cb = n0 + wn * 32 + cl;
  #pragma unroll
  for (int i = 0; i < 2; ++i){
    #pragma unroll
    for (int j = 0; j < 2; ++j){
      #pragma unroll
      for (int r = 0; r < 4; ++r){
        const int row = rb + i * 16 + r;
        const int col = cb + j * 16;
        float v = acc[i][j][r];
        if (bias) v += bias[col];
        outF[(size_t)row * N + col] = v;
      }
    }
  }
}

// ---------------- RoPE cos/sin table: tab[t][fi] = (cos, sin) ----------------
__global__ __launch_bounds__(256) void rope_table(float2* __restrict__ tab){
  const int i = blockIdx.x * 256 + threadIdx.x;   // 65536 = 2048*32
  const int t = i >> 5, fi = i & 31;
  const float invf = powf(10000.0f, -(float)fi / 32.0f);
  float sn, cs;
  sincosf((float)t * invf, &sn, &cs);
  tab[i] = make_float2(cs, sn);
}

// ---------------- RoPE + justnorm + sqk on Q,K in-place (qk layout [bh][t][128], bf16) ----------------
__global__ __launch_bounds__(256) void rope_norm(u16* __restrict__ qk,
                                                 const float* __restrict__ sqk,
                                                 const float2* __restrict__ tab){
  const int lane = threadIdx.x & 63;
  const int idx = blockIdx.x * 4 + (threadIdx.x >> 6);  // row over B*H*T
  const int t = idx & (Tc - 1);
  const int h = (idx >> 11) & (Hc - 1);
  u16* row = qk + (size_t)idx * 128;
  float q = bf2f(row[lane]), k = bf2f(row[64 + lane]);
  const int fi = lane & 31;
  const float2 cssn = tab[t * 32 + fi];
  const float cs = cssn.x, sn = cssn.y;
  float qo = __shfl_xor(q, 32), ko = __shfl_xor(k, 32);
  float rq = (lane < 32) ? -qo : qo;
  float rk = (lane < 32) ? -ko : ko;
  float qn = q * cs + rq * sn;
  float kn = k * cs + rk * sn;
  float sq = waveSum(qn * qn), sk = waveSum(kn * kn);
  float scl = sqk[h * 64 + lane];
  row[lane]      = f2bf(qn / sqrtf(sq) * scl);
  row[64 + lane] = f2bf(kn / sqrtf(sk) * scl);
}

// ---------------- causal flash attention ----------------
// Block = 4 waves = 64 q rows per chunk; complementary chunk pair (i, 31-i).
// NO-MAX softmax (|scores| <= 1/32).  KV in double-buffered XOR-swizzled LDS.
// Counted-vmcnt pipeline (T3/T4): raw s_barriers, vmcnt(4) keeps next-tile
// prefetch in flight across the barrier (no per-step vmcnt(0) drain).
__global__ __launch_bounds__(256) void attn_kernel(const u16* __restrict__ qk,
                                                   const u16* __restrict__ vt,
                                                   float* __restrict__ o){
  __shared__ u16 Kt[2][4096];   // [64 keys][64 dims], XOR-swizzled
  __shared__ u16 Vt[2][4096];   // [64 dims][64 keys], same swizzle
  __shared__ u16 Pt[4][1024];   // per-wave P tile [16 q][64 k], swizzled

  const int tid = threadIdx.x, lane = tid & 63, wave = tid >> 6;
  const int wuni = tid & ~63;
  // bh-clustered XCD remap (512 blocks: xcd = F&7 owns bh in [4*xcd, 4*xcd+4))
  const int F = (int)(blockIdx.y * gridDim.x + blockIdx.x);
  const int xcd = F & 7, ii = F >> 3;
  const int bh = xcd * 4 + (ii & 3);
  const int pr = ii >> 2;                  // pair-chunk index 0..15
  const int g = lane >> 4, cl = lane & 15;
  const u16* qkb = qk + (size_t)bh * Tc * 128;
  const u16* vtb = vt + (size_t)bh * 64 * VTS;
  const int b = bh / Hc, h = bh % Hc;

  auto stage = [&](int sel, int kb){
    #pragma unroll
    for (int it = 0; it < 2; ++it){
      const int idx = it * 256 + tid;        // 0..511 : row=idx>>3, blk=idx&7
      const int row = idx >> 3, blk = idx & 7;
      const int sb = (blk ^ (row & 7)) << 3;
      gload16(qkb + (size_t)(kb + row) * 128 + 64 + sb,
              (char*)Kt[sel] + ((it * 256 + wuni) << 4));
      gload16(vtb + (size_t)row * VTS + kb + sb,
              (char*)Vt[sel] + ((it * 256 + wuni) << 4));
    }
  };

  #pragma unroll 1
  for (int half = 0; half < 2; ++half){
    const int cq = (half == 0) ? pr : 31 - pr;
    const int q0b = cq * 64;
    const int qw = q0b + wave * 16;          // this wave's first q row
    const int nsteps = cq + 1;

    s16x8 qF[2];
    {
      const u16* qrow = qkb + (size_t)(qw + cl) * 128 + (g << 3);
      qF[0] = *(const s16x8*)qrow;
      qF[1] = *(const s16x8*)(qrow + 32);
    }
    f32x4 oF[4] = {};
    float lsum[4] = {0.0f, 0.0f, 0.0f, 0.0f};

    auto compute = [&](int sel, int kb){
      const u16* Kl = Kt[sel];
      const u16* Vl = Vt[sel];
      u16* pw = Pt[wave];
      f32x4 sF[4] = {};
      #pragma unroll
      for (int c16 = 0; c16 < 4; ++c16){
        const int kr = c16 * 16 + cl;
        s16x8 k0 = *(const s16x8*)&Kl[kr * 64 + (((g)     ^ (cl & 7)) << 3)];
        s16x8 k1 = *(const s16x8*)&Kl[kr * 64 + (((4 + g) ^ (cl & 7)) << 3)];
        sF[c16] = __builtin_amdgcn_mfma_f32_16x16x32_bf16(qF[0], k0, sF[c16], 0, 0, 0);
        sF[c16] = __builtin_amdgcn_mfma_f32_16x16x32_bf16(qF[1], k1, sF[c16], 0, 0, 0);
      }
      const float c = 46.16624f;  // 32 * log2(e)
      #pragma unroll
      for (int r = 0; r < 4; ++r){
        const int qg = qw + g * 4 + r;
        const float p0 = (kb + cl      > qg) ? 0.0f : exp2f(sF[0][r] * c);
        const float p1 = (kb + 16 + cl > qg) ? 0.0f : exp2f(sF[1][r] * c);
        const float p2 = (kb + 32 + cl > qg) ? 0.0f : exp2f(sF[2][r] * c);
        const float p3 = (kb + 48 + cl > qg) ? 0.0f : exp2f(sF[3][r] * c);
        lsum[r] += (p0 + p1) + (p2 + p3);
        const int rp = g * 4 + r;
        const int rsw = (rp & 7);
        pw[rp * 64 + ((((cl >> 3)    ) ^ rsw) << 3) + (cl & 7)] = f2bf(p0);
        pw[rp * 64 + ((((cl >> 3) + 2) ^ rsw) << 3) + (cl & 7)] = f2bf(p1);
        pw[rp * 64 + ((((cl >> 3) + 4) ^ rsw) << 3) + (cl & 7)] = f2bf(p2);
        pw[rp * 64 + ((((cl >> 3) + 6) ^ rsw) << 3) + (cl & 7)] = f2bf(p3);
      }
      #pragma unroll
      for (int ksub = 0; ksub < 2; ++ksub){
        s16x8 pF = *(const s16x8*)&pw[cl * 64 + (((ksub * 4 + g) ^ (cl & 7)) << 3)];
        #pragma unroll
        for (int d0 = 0; d0 < 4; ++d0){
          s16x8 vF = *(const s16x8*)&Vl[(d0 * 16 + cl) * 64 + (((ksub * 4 + g) ^ (cl & 7)) << 3)];
          oF[d0] = __builtin_amdgcn_mfma_f32_16x16x32_bf16(pF, vF, oF[d0], 0, 0, 0);
        }
      }
    };

    // counted-vmcnt pipeline: batch kt waits happen one full step after issue
    stage(0, 0);
    for (int kt = 0; kt < nsteps; ++kt){
      const int sel = kt & 1;
      const int kb = kt * 64;
      if (kt + 1 < nsteps){
        stage(sel ^ 1, (kt + 1) * 64);                    // 4 gloads (batch kt+1)
        asm volatile("s_waitcnt vmcnt(4)" ::: "memory");  // batch kt landed; kt+1 in flight
      } else {
        asm volatile("s_waitcnt vmcnt(0)" ::: "memory");  // last tile: full drain
      }
      asm volatile("s_barrier" ::: "memory");             // all waves' batch kt visible
      compute(sel, kb);
      asm volatile("s_barrier" ::: "memory");             // all reads of buf[sel] done
    }

    float invl[4];
    #pragma unroll
    for (int r = 0; r < 4; ++r){
      float l = lsum[r];
      l += __shfl_xor(l, 1);
      l += __shfl_xor(l, 2);
      l += __shfl_xor(l, 4);
      l += __shfl_xor(l, 8);
      invl[r] = 1.0f / l;
    }
    #pragma unroll
    for (int d0 = 0; d0 < 4; ++d0){
      #pragma unroll
      for (int r = 0; r < 4; ++r){
        const int qg = qw + g * 4 + r;
        o[((size_t)(b * Tc + qg)) * DMc + h * 64 + d0 * 16 + cl] = oF[d0][r] * invl[r];
      }
    }
  }
}

// ---------------- row-wise justnorm of 1024-row -> bf16 ----------------
__global__ __launch_bounds__(256) void rownorm1024(const float* __restrict__ in,
                                                   u16* __restrict__ out){
  const int row = blockIdx.x, tid = threadIdx.x;
  const float* r = in + (size_t)row * 1024;
  float v[4]; float ss = 0.0f;
  #pragma unroll
  for (int i = 0; i < 4; ++i){ v[i] = r[tid + i * 256]; ss += v[i] * v[i]; }
  __shared__ float red[4];
  ss = waveSum(ss);
  if ((tid & 63) == 0) red[tid >> 6] = ss;
  __syncthreads();
  const float tot = red[0] + red[1] + red[2] + red[3];
  const float inv = 1.0f / sqrtf(tot);
  #pragma unroll
  for (int i = 0; i < 4; ++i) out[(size_t)row * 1024 + tid + i * 256] = f2bf(v[i] * inv);
}

// ---------------- x2 = justnorm(justnorm(x) + lr*(justnorm(t)-justnorm(x))) -> bf16 only ----------------
__global__ __launch_bounds__(256) void x2_kernel(const float* __restrict__ x,
                                                 const float* __restrict__ t,
                                                 const float* __restrict__ alpha,
                                                 u16* __restrict__ x2b){
  const int row = blockIdx.x, tid = threadIdx.x, lane = tid & 63, wv = tid >> 6;
  const float* xr = x + (size_t)row * 1024;
  const float* tr = t + (size_t)row * 1024;
  float xv[4], tv[4]; float sx = 0.0f, st = 0.0f;
  #pragma unroll
  for (int i = 0; i < 4; ++i){
    xv[i] = xr[tid + i * 256]; sx += xv[i] * xv[i];
    tv[i] = tr[tid + i * 256]; st += tv[i] * tv[i];
  }
  __shared__ float red[8];
  sx = waveSum(sx); st = waveSum(st);
  if (lane == 0){ red[wv] = sx; red[4 + wv] = st; }
  __syncthreads();
  sx = red[0] + red[1] + red[2] + red[3];
  st = red[4] + red[5] + red[6] + red[7];
  const float ix = 1.0f / sqrtf(sx), it = 1.0f / sqrtf(st);
  float yv[4]; float sy = 0.0f;
  #pragma unroll
  for (int i = 0; i < 4; ++i){
    const int c = tid + i * 256;
    const float lr = fabsf(alpha[c] * 1.6f);  // 0.05 / C^-0.5 = 0.05*32
    const float a = xv[i] * ix, bn = tv[i] * it;
    yv[i] = a + lr * (bn - a);
    sy += yv[i] * yv[i];
  }
  sy = waveSum(sy);
  __syncthreads();
  if (lane == 0) red[wv] = sy;
  __syncthreads();
  sy = red[0] + red[1] + red[2] + red[3];
  const float iy = 1.0f / sqrtf(sy);
  #pragma unroll
  for (int i = 0; i < 4; ++i){
    const int c = tid + i * 256;
    x2b[(size_t)row * 1024 + c] = f2bf(yv[i] * iy);
  }
}

// ---------------- uv (bf16, pre-scaled) -> justnorm row 8192 -> res = u*silu(v) in-place ----------------
__global__ __launch_bounds__(256) void uvres_kernel(u16* __restrict__ uv){
  const int row = blockIdx.x, tid = threadIdx.x;
  u16* p = uv + (size_t)row * 8192;
  float uvv[32]; float ss = 0.0f;
  const u16x8* su = (const u16x8*)(p + tid * 16);
  const u16x8* sv = (const u16x8*)(p + 4096 + tid * 16);
  u16x8 a0 = su[0], a1 = su[1], b0 = sv[0], b1 = sv[1];
  #pragma unroll
  for (int j = 0; j < 8; ++j){
    uvv[j]      = bf2f(a0[j]); uvv[8 + j]  = bf2f(a1[j]);
    uvv[16 + j] = bf2f(b0[j]); uvv[24 + j] = bf2f(b1[j]);
  }
  #pragma unroll
  for (int j = 0; j < 32; ++j) ss += uvv[j] * uvv[j];
  __shared__ float red[4];
  ss = waveSum(ss);
  if ((tid & 63) == 0) red[tid >> 6] = ss;
  __syncthreads();
  const float tot = red[0] + red[1] + red[2] + red[3];
  const float inv = 1.0f / sqrtf(tot);
  #pragma unroll
  for (int j = 0; j < 16; ++j){
    const float un = uvv[j] * inv;
    const float vn = uvv[16 + j] * inv;
    const float sil = vn / (1.0f + expf(-vn));
    p[tid * 16 + j] = f2bf(un * sil);
  }
}

// ---------------- final: justnorm(justnorm(x2) + lr2*(justnorm(t2)-justnorm(x2))) ----------------
// x2 read as bf16 (same buffer Wu consumed); t2 fp32.
__global__ __launch_bounds__(256) void final_kernel(const u16* __restrict__ x2,
                                                    const float* __restrict__ t2,
                                                    const float* __restrict__ alpha,
                                                    float* __restrict__ out){
  const int row = blockIdx.x, tid = threadIdx.x, lane = tid & 63, wv = tid >> 6;
  const u16* a = x2 + (size_t)row * 1024;
  const float* b = t2 + (size_t)row * 1024;
  float av[4], bv[4]; float sa = 0.0f, sb = 0.0f;
  #pragma unroll
  for (int i = 0; i < 4; ++i){
    av[i] = bf2f(a[tid + i * 256]); sa += av[i] * av[i];
    bv[i] = b[tid + i * 256]; sb += bv[i] * bv[i];
  }
  __shared__ float red[8];
  sa = waveSum(sa); sb = waveSum(sb);
  if (lane == 0){ red[wv] = sa; red[4 + wv] = sb; }
  __syncthreads();
  sa = red[0] + red[1] + red[2] + red[3];
  sb = red[4] + red[5] + red[6] + red[7];
  const float ia = 1.0f / sqrtf(sa), ib = 1.0f / sqrtf(sb);
  float yv[4]; float sy = 0.0f;
  #pragma unroll
  for (int i = 0; i < 4; ++i){
    const int c = tid + i * 256;
    const float lr = fabsf(alpha[c] * 0.05f);
    const float an = av[i] * ia, bn = bv[i] * ib;
    yv[i] = an + lr * (bn - an);
    sy += yv[i] * yv[i];
  }
  sy = waveSum(sy);
  __syncthreads();
  if (lane == 0) red[wv] = sy;
  __syncthreads();
  sy = red[0] + red[1] + red[2] + red[3];
  const float iy = 1.0f / sqrtf(sy);
  #pragma unroll
  for (int i = 0; i < 4; ++i)
    out[(size_t)row * 1024 + tid + i * 256] = yv[i] * iy;
}

extern "C" void kernel_launch(void* const* d_in, const int* in_sizes, int n_in,
                              void* d_out, int out_size, void* d_ws, size_t ws_size,
                              hipStream_t stream) {
  const float* x          = (const float*)d_in[0];
  const float* Wqkv       = (const float*)d_in[1];
  const float* sqk        = (const float*)d_in[2];
  const float* W_O        = (const float*)d_in[3];
  const float* attn_alpha = (const float*)d_in[4];
  const float* Wu_w       = (const float*)d_in[5];
  const float* Wu_b       = (const float*)d_in[6];
  const float* suv        = (const float*)d_in[7];
  const float* Wv_w       = (const float*)d_in[8];
  const float* Wv_b       = (const float*)d_in[9];
  const float* mlp_alpha  = (const float*)d_in[10];
  float* out = (float*)d_out;

  char* ws = (char*)d_ws;
  // workspace layout (128 MiB total, aliased) — identical to round 13:
  u16*   wbuf = (u16*)(ws);                       // 16 MiB: bf16 weights (reused per GEMM); rope table after QKV
  u16*   abuf = (u16*)(ws + 16777216);            //  8 MiB: bf16 A operand (xb -> ob_norm -> x2b; x2b read by final)
  u16*   qkb  = (u16*)(ws + 25165824);            // 16 MiB: Q|K [bh][t][128]; later tbuf fp32
  float* tbuf = (float*)(ws + 25165824);
  float* aout = (float*)(ws + 50331648);          // 16 MiB: attn out fp32
  u16*   uvb  = (u16*)(ws + 67108864);            // 64 MiB: uv bf16 (res overwrites u-half)
  u16*   vtb  = (u16*)(ws + 67108864);            // 8.5 MiB: V^T [bh][64][VTS] (dead before uv GEMM)

  const int M = Bc * Tc;  // 4096

  auto cvt = [&](const float* in, u16* o, int n){
    int n4 = n / 4;
    int blocks = (n4 + 255) / 256;
    if (blocks > 4096) blocks = 4096;
    cvt_f32_bf16<<<dim3(blocks), dim3(256), 0, stream>>>(in, o, n4);
  };

  // 1. qkv = x @ Wqkv^T  -> Q|K packed [bh][t][128] + V^T [bh][d][VTS]
  cvt(x, abuf, M * DMc);
  cvt(Wqkv, wbuf, Hc * 192 * DMc);
  gemm_bt<1><<<dim3(3072 / 128, M / 128), 256, 0, stream>>>(
      abuf, DMc, wbuf, nullptr, qkb, vtb, nullptr, nullptr, 0.0f, M, 3072, DMc);

  // 2. RoPE table (into now-idle wbuf) + RoPE/justnorm/sqk on Q,K
  rope_table<<<dim3(Tc * 32 / 256), 256, 0, stream>>>((float2*)wbuf);
  rope_norm<<<dim3(Bc * Hc * Tc / 4), 256, 0, stream>>>(qkb, sqk, (const float2*)wbuf);

  // 3. causal flash attention -> aout (b,t,h*64+d) fp32
  attn_kernel<<<dim3(Tc / 128, Bc * Hc), 256, 0, stream>>>(qkb, vtb, aout);

  // 4. justnorm rows -> bf16, then t = . @ W_O^T (fp32)  [64-tile GEMM, BK=128]
  rownorm1024<<<dim3(M), 256, 0, stream>>>(aout, abuf);
  cvt(W_O, wbuf, DMc * DMc);
  gemm64_bt<<<dim3(DMc / 64, M / 64), 256, 0, stream>>>(
      abuf, DMc, wbuf, DMc, tbuf, nullptr, M, DMc, DMc);

  // 5. x2 residual mix -> abuf (bf16 only; also read by final_kernel)
  x2_kernel<<<dim3(M), 256, 0, stream>>>(x, tbuf, attn_alpha, abuf);

  // 6. uv = (x2 @ Wu^T + b) * suv * 32  (bf16)  [256² 8-phase pipeline]
  cvt(Wu_w, wbuf, 8192 * DMc);
  gemm256_bt<<<dim3(8192 / 256, M / 256), 512, 0, stream>>>(
      abuf, DMc, wbuf, DMc, uvb, Wu_b, suv, 32.0f, M, 8192, DMc);

  // 7. row-norm 8192 + u*silu(v) in-place into u half
  uvres_kernel<<<dim3(M), 256, 0, stream>>>(uvb);

  // 8. t2 = res @ Wv^T + b (fp32)  [64-tile GEMM, BK=128]
  cvt(Wv_w, wbuf, DMc * 4096);
  gemm64_bt<<<dim3(DMc / 64, M / 64), 256, 0, stream>>>(
      uvb, 8192, wbuf, 4096, tbuf, Wv_b, M, DMc, 4096);

  // 9. final residual mix -> d_out (x2 from abuf bf16)
  final_kernel<<<dim3(M), 256, 0, stream>>>(abuf, tbuf, mlp_alpha, out);
}

// Round 15
// 307.144 us; speedup vs baseline: 1.0175x; 1.0175x over previous
//
#include <hip/hip_runtime.h>
#include <cstdint>
#include <cstddef>

#define DEVI __device__ __forceinline__

typedef __attribute__((ext_vector_type(8))) short s16x8;
typedef __attribute__((ext_vector_type(8))) unsigned short u16x8;
typedef __attribute__((ext_vector_type(4))) float f32x4;
typedef unsigned short u16;

static constexpr int Bc = 2, Tc = 2048, Hc = 16, DMc = 1024;
static constexpr int VTS = 2064;  // V^T row stride in u16 (4128B: non-pow2, 16B-aligned)

DEVI float bf2f(u16 u){ unsigned int x = ((unsigned int)u) << 16; return __builtin_bit_cast(float, x); }
DEVI u16 f2bf(float f){
  unsigned int u = __builtin_bit_cast(unsigned int, f);
  u += 0x7FFFu + ((u >> 16) & 1u);
  return (u16)(u >> 16);
}

DEVI float waveSum(float v){
  #pragma unroll
  for (int m = 1; m < 64; m <<= 1) v += __shfl_xor(v, m);
  return v;
}

DEVI void gload16(const void* g, void* l){
  __builtin_amdgcn_global_load_lds((const __attribute__((address_space(1))) void*)g,
                                   (__attribute__((address_space(3))) void*)l, 16, 0, 0);
}

// ---------------- fp32 -> bf16 convert (single buffer; used for Wu) ----------------
__global__ __launch_bounds__(256) void cvt_f32_bf16(const float* __restrict__ in,
                                                    u16* __restrict__ out, int n4){
  int i = blockIdx.x * blockDim.x + threadIdx.x;
  int stride = gridDim.x * blockDim.x;
  for (int idx = i; idx < n4; idx += stride){
    float4 v = ((const float4*)in)[idx];
    ushort4 o;
    o.x = f2bf(v.x); o.y = f2bf(v.y); o.z = f2bf(v.z); o.w = f2bf(v.w);
    ((ushort4*)out)[idx] = o;
  }
}

// ---------------- batched fp32 -> bf16: x | Wqkv | W_O | Wv in one launch ----------------
// segments (float4 units): x 1048576 | wqkv 786432 | wo 262144 | wv 1048576 = 3145728 total
__global__ __launch_bounds__(256) void cvt_all(
    const float* __restrict__ x,  const float* __restrict__ wqkv,
    const float* __restrict__ wo, const float* __restrict__ wv,
    u16* __restrict__ xb, u16* __restrict__ wqkvb,
    u16* __restrict__ wob, u16* __restrict__ wvb)
{
  const int total = 3145728;
  int i = blockIdx.x * blockDim.x + threadIdx.x;
  const int stride = gridDim.x * blockDim.x;
  for (int idx = i; idx < total; idx += stride){
    const float4* s; ushort4* d; int l;
    if (idx < 1048576){      s = (const float4*)x;    d = (ushort4*)xb;    l = idx; }
    else if (idx < 1835008){ s = (const float4*)wqkv; d = (ushort4*)wqkvb; l = idx - 1048576; }
    else if (idx < 2097152){ s = (const float4*)wo;   d = (ushort4*)wob;   l = idx - 1835008; }
    else {                   s = (const float4*)wv;   d = (ushort4*)wvb;   l = idx - 2097152; }
    float4 v = s[l];
    ushort4 o;
    o.x = f2bf(v.x); o.y = f2bf(v.y); o.z = f2bf(v.z); o.w = f2bf(v.w);
    d[l] = o;
  }
}

// ---------------- GEMM 256x256, BK=64, 8-phase counted-vmcnt pipeline ----------------
__global__ __launch_bounds__(512, 1) void gemm256_bt(
    const u16* __restrict__ A, int lda, const u16* __restrict__ W, int ldw,
    u16* __restrict__ outB, const float* __restrict__ bias,
    const float* __restrict__ scale, float smul,
    int M, int N, int K)
{
  __shared__ u16 lds8[65536];   // 128 KiB: A slots [0,32768), B slots [32768,65536)
  const int tid = threadIdx.x, lane = tid & 63, wave = tid >> 6;
  const int wm = wave >> 2, wn = wave & 3;
  const int g = lane >> 4, cl = lane & 15;
  // n-chunked XCD swizzle (gridDim.x % 8 == 0)
  const int F = blockIdx.y * gridDim.x + blockIdx.x;
  const int xcd = F & 7, i0 = F >> 3;
  const int NCH = gridDim.x >> 3;
  const int n0 = (xcd * NCH + i0 % NCH) * 256;
  const int m0 = (i0 / NCH) * 256;

  const int nt = K >> 6;         // K-tiles
  const int iters = nt >> 1;     // 2 K-tiles per iteration
  const int wuni = tid & ~63;

  f32x4 acc[8][4] = {};

  auto stageA = [&](int h, int t){
    char* dst = (char*)(lds8 + (size_t)(2 * (t & 1) + h) * 8192);
    const int k0 = t << 6;
    #pragma unroll
    for (int j = 0; j < 2; ++j){
      const int idx = j * 512 + tid;            // 0..1023: row=idx>>3, blk=idx&7
      const int row = idx >> 3;
      const int sb = ((idx & 7) ^ (row & 7)) << 3;
      gload16(A + (size_t)(m0 + h * 128 + row) * lda + k0 + sb,
              dst + ((j * 512 + wuni) << 4));
    }
  };
  auto stageB = [&](int h, int t){
    char* dst = (char*)(lds8 + 32768 + (size_t)(2 * (t & 1) + h) * 8192);
    const int k0 = t << 6;
    #pragma unroll
    for (int j = 0; j < 2; ++j){
      const int idx = j * 512 + tid;
      const int row = idx >> 3;
      const int sb = ((idx & 7) ^ (row & 7)) << 3;
      gload16(W + (size_t)(n0 + h * 128 + row) * ldw + k0 + sb,
              dst + ((j * 512 + wuni) << 4));
    }
  };

  // prologue: B(0), A(0), B(1) = 12 gloads
  stageB(0, 0); stageB(1, 0); stageA(0, 0); stageA(1, 0); stageB(0, 1); stageB(1, 1);

  s16x8 bF[4][2];
  for (int v = 0; v < iters; ++v){
    const bool lastIt = (v == iters - 1);
    #pragma unroll
    for (int p = 0; p < 8; ++p){
      const int tt = p >> 2, q = p & 3;
      const int t = 2 * v + tt;
      // stage schedule (slot legality: re-stage only after last read's barrier)
      if (p == 0)      stageA(0, 2 * v + 1);
      else if (p == 1) stageA(1, 2 * v + 1);
      else if (p == 2){ if (2 * v + 2 < nt) stageB(0, 2 * v + 2); }
      else if (p == 3){ if (2 * v + 2 < nt) stageB(1, 2 * v + 2); }
      else if (p == 4){ if (2 * v + 2 < nt) stageA(0, 2 * v + 2); }
      else if (p == 5){ if (2 * v + 2 < nt) stageA(1, 2 * v + 2); }
      else if (p == 6){ if (2 * v + 3 < nt) stageB(0, 2 * v + 3); }
      else            { if (2 * v + 3 < nt) stageB(1, 2 * v + 3); }

      if (p == 0) asm volatile("s_waitcnt vmcnt(6)" ::: "memory");
      if (p == 4){
        if (lastIt) asm volatile("s_waitcnt vmcnt(0)" ::: "memory");
        else        asm volatile("s_waitcnt vmcnt(6)" ::: "memory");
      }

      // ds_read register subtile
      const int abase = (2 * (t & 1) + wm) * 8192;
      s16x8 aF[2][2];
      #pragma unroll
      for (int i2 = 0; i2 < 2; ++i2){
        const int r = (2 * q + i2) * 16 + cl;
        #pragma unroll
        for (int kk = 0; kk < 2; ++kk)
          aF[i2][kk] = *(const s16x8*)&lds8[abase + r * 64 + (((kk * 4 + g) ^ (r & 7)) << 3)];
      }
      if (q == 0){
        const int bbase = 32768 + (2 * (t & 1) + (wn >> 1)) * 8192;
        #pragma unroll
        for (int j = 0; j < 4; ++j){
          const int rb2 = (wn & 1) * 64 + j * 16 + cl;
          #pragma unroll
          for (int kk = 0; kk < 2; ++kk)
            bF[j][kk] = *(const s16x8*)&lds8[bbase + rb2 * 64 + (((kk * 4 + g) ^ (rb2 & 7)) << 3)];
        }
      }

      asm volatile("s_barrier" ::: "memory");
      __builtin_amdgcn_s_setprio(1);
      #pragma unroll
      for (int i2 = 0; i2 < 2; ++i2)
        #pragma unroll
        for (int j = 0; j < 4; ++j)
          #pragma unroll
          for (int kk = 0; kk < 2; ++kk)
            acc[2 * q + i2][j] = __builtin_amdgcn_mfma_f32_16x16x32_bf16(
                aF[i2][kk], bF[j][kk], acc[2 * q + i2][j], 0, 0, 0);
      __builtin_amdgcn_s_setprio(0);
      asm volatile("s_barrier" ::: "memory");
    }
  }

  // epilogue
  const int rb = m0 + wm * 128 + (g << 2);
  const int cb = n0 + wn * 64 + cl;
  #pragma unroll
  for (int i = 0; i < 8; ++i){
    #pragma unroll
    for (int j = 0; j < 4; ++j){
      const int col = cb + j * 16;
      const float sc = scale[col] * smul;
      const float bi = bias[col];
      #pragma unroll
      for (int r = 0; r < 4; ++r){
        const int row = rb + i * 16 + r;
        outB[(size_t)row * N + col] = f2bf((acc[i][j][r] + bi) * sc);
      }
    }
  }
}

// ---------------- GEMM 128x128, BK=64, XOR-swizzled LDS (conflict-free) ----------------
// EPI 0: fp32 out (+ optional bias)
// EPI 1: bf16 out: Q,K -> qk[bh][t][128]; V -> transposed vt[bh][d][VTS]
template<int EPI>
__global__ __launch_bounds__(256) void gemm_bt(
    const u16* __restrict__ A, int lda, const u16* __restrict__ W,
    float* __restrict__ outF, u16* __restrict__ outB, u16* __restrict__ outB2,
    const float* __restrict__ bias, const float* __restrict__ scale, float smul,
    int M, int N, int K)
{
  __shared__ u16 lA[128 * 64];
  __shared__ u16 lB[128 * 64];
  const int tid = threadIdx.x, lane = tid & 63;
  const int wave = tid >> 6, wm = wave >> 1, wn = wave & 1;
  const int g = lane >> 4, cl = lane & 15;
  // n-chunked XCD swizzle (requires gridDim.x % 8 == 0; bijective)
  const int F = blockIdx.y * gridDim.x + blockIdx.x;
  const int xcd = F & 7, i0 = F >> 3;
  const int NCH = gridDim.x >> 3;
  const int n0 = (xcd * NCH + i0 % NCH) * 128;
  const int m0 = (i0 / NCH) * 128;
  f32x4 acc[4][4] = {};
  const int kT = K >> 6;
  char* lAc = (char*)lA;
  char* lBc = (char*)lB;
  const int wuni = (tid & ~63);

  for (int kt = 0; kt < kT; ++kt){
    const int k0 = kt << 6;
    __syncthreads();
    #pragma unroll
    for (int j = 0; j < 4; ++j){
      const int idx = j * 256 + tid;            // 0..1023: row=idx>>3, blk=idx&7
      const int row = idx >> 3;
      const int sb = ((idx & 7) ^ (row & 7)) << 3;  // pre-swizzled source col-block
      gload16(A + (size_t)(m0 + row) * lda + k0 + sb,
              lAc + ((j * 256 + wuni) << 4));
    }
    #pragma unroll
    for (int j = 0; j < 4; ++j){
      const int idx = j * 256 + tid;
      const int row = idx >> 3;
      const int sb = ((idx & 7) ^ (row & 7)) << 3;
      gload16(W + (size_t)(n0 + row) * K + k0 + sb,
              lBc + ((j * 256 + wuni) << 4));
    }
    __syncthreads();

    #pragma unroll
    for (int kk = 0; kk < 2; ++kk){
      s16x8 aF[4], bF[4];
      #pragma unroll
      for (int i = 0; i < 4; ++i){
        const int ra = wm * 64 + i * 16 + cl;
        aF[i] = *(const s16x8*)&lA[ra * 64 + (((kk * 4 + g) ^ (ra & 7)) << 3)];
      }
      #pragma unroll
      for (int j = 0; j < 4; ++j){
        const int rbr = wn * 64 + j * 16 + cl;
        bF[j] = *(const s16x8*)&lB[rbr * 64 + (((kk * 4 + g) ^ (rbr & 7)) << 3)];
      }
      #pragma unroll
      for (int i = 0; i < 4; ++i)
        #pragma unroll
        for (int j = 0; j < 4; ++j)
          acc[i][j] = __builtin_amdgcn_mfma_f32_16x16x32_bf16(aF[i], bF[j], acc[i][j], 0, 0, 0);
    }
  }

  const int rb = m0 + wm * 64 + (g << 2);
  const int cb = n0 + wn * 64 + cl;
  #pragma unroll
  for (int i = 0; i < 4; ++i){
    #pragma unroll
    for (int j = 0; j < 4; ++j){
      #pragma unroll
      for (int r = 0; r < 4; ++r){
        const int row = rb + i * 16 + r;
        const int col = cb + j * 16;
        float v = acc[i][j][r];
        if (EPI == 0){
          if (bias) v += bias[col];
          outF[(size_t)row * N + col] = v;
        } else if (EPI == 1){
          const int b = row >> 11;           // T = 2048
          const int t = row & (Tc - 1);
          const int h = col / 192;
          const int e = col - h * 192;
          const int bh = b * Hc + h;
          if (e < 128){
            outB[((size_t)bh * Tc + t) * 128 + e] = f2bf(v);         // Q|K packed
          } else {
            outB2[((size_t)bh * 64 + (e - 128)) * VTS + t] = f2bf(v); // V^T [d][VTS]
          }
        } else {
          v = (v + bias[col]) * (scale[col] * smul);
          outB[(size_t)row * N + col] = f2bf(v);
        }
      }
    }
  }
}

// ---------------- GEMM 64x64, BK=128, XOR-swizzled LDS (conflict-free) ----------------
__global__ __launch_bounds__(256) void gemm64_bt(
    const u16* __restrict__ A, int lda, const u16* __restrict__ W, int ldw,
    float* __restrict__ outF, const float* __restrict__ bias,
    int M, int N, int K)
{
  __shared__ u16 lA[64 * 128];
  __shared__ u16 lB[64 * 128];
  const int tid = threadIdx.x, lane = tid & 63;
  const int wave = tid >> 6, wm = wave >> 1, wn = wave & 1;
  const int g = lane >> 4, cl = lane & 15;
  // XCD-chunked bijective swizzle (nwg % 8 == 0)
  const int nwg = gridDim.x * gridDim.y;
  int flat = blockIdx.y * gridDim.x + blockIdx.x;
  flat = (flat & 7) * (nwg >> 3) + (flat >> 3);
  const int n0 = (flat % gridDim.x) * 64;
  const int m0 = (flat / gridDim.x) * 64;
  f32x4 acc[2][2] = {};
  const int kT = K >> 7;
  const int wuni = tid & ~63;

  for (int kt = 0; kt < kT; ++kt){
    const int k0 = kt << 7;
    __syncthreads();
    #pragma unroll
    for (int it = 0; it < 4; ++it){
      const int idx = it * 256 + tid;        // 0..1023: row=idx>>4, blk=idx&15 (16x 16B/row)
      const int row = idx >> 4, blk = idx & 15;
      const int sb = ((blk & 8) | ((blk & 7) ^ (row & 7))) << 3;  // swizzle within 128B halves
      gload16(A + (size_t)(m0 + row) * lda + k0 + sb,
              (char*)lA + ((it * 256 + wuni) << 4));
      gload16(W + (size_t)(n0 + row) * ldw + k0 + sb,
              (char*)lB + ((it * 256 + wuni) << 4));
    }
    __syncthreads();

    #pragma unroll
    for (int kk = 0; kk < 4; ++kk){
      s16x8 aF[2], bF[2];
      #pragma unroll
      for (int i = 0; i < 2; ++i){
        const int ra = wm * 32 + i * 16 + cl;
        const int ba = kk * 4 + g;
        const int sa = ((ba & 8) | ((ba & 7) ^ (ra & 7))) << 3;
        aF[i] = *(const s16x8*)&lA[ra * 128 + sa];
        const int rbr = wn * 32 + i * 16 + cl;
        const int sbw = ((ba & 8) | ((ba & 7) ^ (rbr & 7))) << 3;
        bF[i] = *(const s16x8*)&lB[rbr * 128 + sbw];
      }
      #pragma unroll
      for (int i = 0; i < 2; ++i)
        #pragma unroll
        for (int j = 0; j < 2; ++j)
          acc[i][j] = __builtin_amdgcn_mfma_f32_16x16x32_bf16(aF[i], bF[j], acc[i][j], 0, 0, 0);
    }
  }

  const int rb = m0 + wm * 32 + (g << 2);
  const int cb = n0 + wn * 32 + cl;
  #pragma unroll
  for (int i = 0; i < 2; ++i){
    #pragma unroll
    for (int j = 0; j < 2; ++j){
      #pragma unroll
      for (int r = 0; r < 4; ++r){
        const int row = rb + i * 16 + r;
        const int col = cb + j * 16;
        float v = acc[i][j][r];
        if (bias) v += bias[col];
        outF[(size_t)row * N + col] = v;
      }
    }
  }
}

// ---------------- RoPE cos/sin table: tab[t][fi] = (cos, sin) ----------------
__global__ __launch_bounds__(256) void rope_table(float2* __restrict__ tab){
  const int i = blockIdx.x * 256 + threadIdx.x;   // 65536 = 2048*32
  const int t = i >> 5, fi = i & 31;
  const float invf = powf(10000.0f, -(float)fi / 32.0f);
  float sn, cs;
  sincosf((float)t * invf, &sn, &cs);
  tab[i] = make_float2(cs, sn);
}

// ---------------- RoPE + justnorm + sqk on Q,K in-place (qk layout [bh][t][128], bf16) ----------------
__global__ __launch_bounds__(256) void rope_norm(u16* __restrict__ qk,
                                                 const float* __restrict__ sqk,
                                                 const float2* __restrict__ tab){
  const int lane = threadIdx.x & 63;
  const int idx = blockIdx.x * 4 + (threadIdx.x >> 6);  // row over B*H*T
  const int t = idx & (Tc - 1);
  const int h = (idx >> 11) & (Hc - 1);
  u16* row = qk + (size_t)idx * 128;
  float q = bf2f(row[lane]), k = bf2f(row[64 + lane]);
  const int fi = lane & 31;
  const float2 cssn = tab[t * 32 + fi];
  const float cs = cssn.x, sn = cssn.y;
  float qo = __shfl_xor(q, 32), ko = __shfl_xor(k, 32);
  float rq = (lane < 32) ? -qo : qo;
  float rk = (lane < 32) ? -ko : ko;
  float qn = q * cs + rq * sn;
  float kn = k * cs + rk * sn;
  float sq = waveSum(qn * qn), sk = waveSum(kn * kn);
  float scl = sqk[h * 64 + lane];
  row[lane]      = f2bf(qn / sqrtf(sq) * scl);
  row[64 + lane] = f2bf(kn / sqrtf(sk) * scl);
}

// ---------------- causal flash attention ----------------
// Block = 4 waves = 64 q rows per chunk; complementary chunk pair (i, 31-i).
// NO-MAX softmax (|scores| <= 1/32).  KV in double-buffered XOR-swizzled LDS.
// Counted-vmcnt pipeline: raw s_barriers, vmcnt(4) keeps next-tile prefetch in flight.
__global__ __launch_bounds__(256) void attn_kernel(const u16* __restrict__ qk,
                                                   const u16* __restrict__ vt,
                                                   float* __restrict__ o){
  __shared__ u16 Kt[2][4096];   // [64 keys][64 dims], XOR-swizzled
  __shared__ u16 Vt[2][4096];   // [64 dims][64 keys], same swizzle
  __shared__ u16 Pt[4][1024];   // per-wave P tile [16 q][64 k], swizzled

  const int tid = threadIdx.x, lane = tid & 63, wave = tid >> 6;
  const int wuni = tid & ~63;
  // bh-clustered XCD remap (512 blocks: xcd = F&7 owns bh in [4*xcd, 4*xcd+4))
  const int F = (int)(blockIdx.y * gridDim.x + blockIdx.x);
  const int xcd = F & 7, ii = F >> 3;
  const int bh = xcd * 4 + (ii & 3);
  const int pr = ii >> 2;                  // pair-chunk index 0..15
  const int g = lane >> 4, cl = lane & 15;
  const u16* qkb = qk + (size_t)bh * Tc * 128;
  const u16* vtb = vt + (size_t)bh * 64 * VTS;
  const int b = bh / Hc, h = bh % Hc;

  auto stage = [&](int sel, int kb){
    #pragma unroll
    for (int it = 0; it < 2; ++it){
      const int idx = it * 256 + tid;        // 0..511 : row=idx>>3, blk=idx&7
      const int row = idx >> 3, blk = idx & 7;
      const int sb = (blk ^ (row & 7)) << 3;
      gload16(qkb + (size_t)(kb + row) * 128 + 64 + sb,
              (char*)Kt[sel] + ((it * 256 + wuni) << 4));
      gload16(vtb + (size_t)row * VTS + kb + sb,
              (char*)Vt[sel] + ((it * 256 + wuni) << 4));
    }
  };

  #pragma unroll 1
  for (int half = 0; half < 2; ++half){
    const int cq = (half == 0) ? pr : 31 - pr;
    const int q0b = cq * 64;
    const int qw = q0b + wave * 16;          // this wave's first q row
    const int nsteps = cq + 1;

    s16x8 qF[2];
    {
      const u16* qrow = qkb + (size_t)(qw + cl) * 128 + (g << 3);
      qF[0] = *(const s16x8*)qrow;
      qF[1] = *(const s16x8*)(qrow + 32);
    }
    f32x4 oF[4] = {};
    float lsum[4] = {0.0f, 0.0f, 0.0f, 0.0f};

    auto compute = [&](int sel, int kb){
      const u16* Kl = Kt[sel];
      const u16* Vl = Vt[sel];
      u16* pw = Pt[wave];
      f32x4 sF[4] = {};
      #pragma unroll
      for (int c16 = 0; c16 < 4; ++c16){
        const int kr = c16 * 16 + cl;
        s16x8 k0 = *(const s16x8*)&Kl[kr * 64 + (((g)     ^ (cl & 7)) << 3)];
        s16x8 k1 = *(const s16x8*)&Kl[kr * 64 + (((4 + g) ^ (cl & 7)) << 3)];
        sF[c16] = __builtin_amdgcn_mfma_f32_16x16x32_bf16(qF[0], k0, sF[c16], 0, 0, 0);
        sF[c16] = __builtin_amdgcn_mfma_f32_16x16x32_bf16(qF[1], k1, sF[c16], 0, 0, 0);
      }
      const float c = 46.16624f;  // 32 * log2(e)
      #pragma unroll
      for (int r = 0; r < 4; ++r){
        const int qg = qw + g * 4 + r;
        const float p0 = (kb + cl      > qg) ? 0.0f : exp2f(sF[0][r] * c);
        const float p1 = (kb + 16 + cl > qg) ? 0.0f : exp2f(sF[1][r] * c);
        const float p2 = (kb + 32 + cl > qg) ? 0.0f : exp2f(sF[2][r] * c);
        const float p3 = (kb + 48 + cl > qg) ? 0.0f : exp2f(sF[3][r] * c);
        lsum[r] += (p0 + p1) + (p2 + p3);
        const int rp = g * 4 + r;
        const int rsw = (rp & 7);
        pw[rp * 64 + ((((cl >> 3)    ) ^ rsw) << 3) + (cl & 7)] = f2bf(p0);
        pw[rp * 64 + ((((cl >> 3) + 2) ^ rsw) << 3) + (cl & 7)] = f2bf(p1);
        pw[rp * 64 + ((((cl >> 3) + 4) ^ rsw) << 3) + (cl & 7)] = f2bf(p2);
        pw[rp * 64 + ((((cl >> 3) + 6) ^ rsw) << 3) + (cl & 7)] = f2bf(p3);
      }
      #pragma unroll
      for (int ksub = 0; ksub < 2; ++ksub){
        s16x8 pF = *(const s16x8*)&pw[cl * 64 + (((ksub * 4 + g) ^ (cl & 7)) << 3)];
        #pragma unroll
        for (int d0 = 0; d0 < 4; ++d0){
          s16x8 vF = *(const s16x8*)&Vl[(d0 * 16 + cl) * 64 + (((ksub * 4 + g) ^ (cl & 7)) << 3)];
          oF[d0] = __builtin_amdgcn_mfma_f32_16x16x32_bf16(pF, vF, oF[d0], 0, 0, 0);
        }
      }
    };

    // counted-vmcnt pipeline: batch kt waits happen one full step after issue
    stage(0, 0);
    for (int kt = 0; kt < nsteps; ++kt){
      const int sel = kt & 1;
      const int kb = kt * 64;
      if (kt + 1 < nsteps){
        stage(sel ^ 1, (kt + 1) * 64);                    // 4 gloads (batch kt+1)
        asm volatile("s_waitcnt vmcnt(4)" ::: "memory");  // batch kt landed; kt+1 in flight
      } else {
        asm volatile("s_waitcnt vmcnt(0)" ::: "memory");  // last tile: full drain
      }
      asm volatile("s_barrier" ::: "memory");             // all waves' batch kt visible
      compute(sel, kb);
      asm volatile("s_barrier" ::: "memory");             // all reads of buf[sel] done
    }

    float invl[4];
    #pragma unroll
    for (int r = 0; r < 4; ++r){
      float l = lsum[r];
      l += __shfl_xor(l, 1);
      l += __shfl_xor(l, 2);
      l += __shfl_xor(l, 4);
      l += __shfl_xor(l, 8);
      invl[r] = 1.0f / l;
    }
    #pragma unroll
    for (int d0 = 0; d0 < 4; ++d0){
      #pragma unroll
      for (int r = 0; r < 4; ++r){
        const int qg = qw + g * 4 + r;
        o[((size_t)(b * Tc + qg)) * DMc + h * 64 + d0 * 16 + cl] = oF[d0][r] * invl[r];
      }
    }
  }
}

// ---------------- row-wise justnorm of 1024-row -> bf16 ----------------
__global__ __launch_bounds__(256) void rownorm1024(const float* __restrict__ in,
                                                   u16* __restrict__ out){
  const int row = blockIdx.x, tid = threadIdx.x;
  const float* r = in + (size_t)row * 1024;
  float v[4]; float ss = 0.0f;
  #pragma unroll
  for (int i = 0; i < 4; ++i){ v[i] = r[tid + i * 256]; ss += v[i] * v[i]; }
  __shared__ float red[4];
  ss = waveSum(ss);
  if ((tid & 63) == 0) red[tid >> 6] = ss;
  __syncthreads();
  const float tot = red[0] + red[1] + red[2] + red[3];
  const float inv = 1.0f / sqrtf(tot);
  #pragma unroll
  for (int i = 0; i < 4; ++i) out[(size_t)row * 1024 + tid + i * 256] = f2bf(v[i] * inv);
}

// ---------------- x2 = justnorm(justnorm(x) + lr*(justnorm(t)-justnorm(x))) -> bf16 only ----------------
__global__ __launch_bounds__(256) void x2_kernel(const float* __restrict__ x,
                                                 const float* __restrict__ t,
                                                 const float* __restrict__ alpha,
                                                 u16* __restrict__ x2b){
  const int row = blockIdx.x, tid = threadIdx.x, lane = tid & 63, wv = tid >> 6;
  const float* xr = x + (size_t)row * 1024;
  const float* tr = t + (size_t)row * 1024;
  float xv[4], tv[4]; float sx = 0.0f, st = 0.0f;
  #pragma unroll
  for (int i = 0; i < 4; ++i){
    xv[i] = xr[tid + i * 256]; sx += xv[i] * xv[i];
    tv[i] = tr[tid + i * 256]; st += tv[i] * tv[i];
  }
  __shared__ float red[8];
  sx = waveSum(sx); st = waveSum(st);
  if (lane == 0){ red[wv] = sx; red[4 + wv] = st; }
  __syncthreads();
  sx = red[0] + red[1] + red[2] + red[3];
  st = red[4] + red[5] + red[6] + red[7];
  const float ix = 1.0f / sqrtf(sx), it = 1.0f / sqrtf(st);
  float yv[4]; float sy = 0.0f;
  #pragma unroll
  for (int i = 0; i < 4; ++i){
    const int c = tid + i * 256;
    const float lr = fabsf(alpha[c] * 1.6f);  // 0.05 / C^-0.5 = 0.05*32
    const float a = xv[i] * ix, bn = tv[i] * it;
    yv[i] = a + lr * (bn - a);
    sy += yv[i] * yv[i];
  }
  sy = waveSum(sy);
  __syncthreads();
  if (lane == 0) red[wv] = sy;
  __syncthreads();
  sy = red[0] + red[1] + red[2] + red[3];
  const float iy = 1.0f / sqrtf(sy);
  #pragma unroll
  for (int i = 0; i < 4; ++i){
    const int c = tid + i * 256;
    x2b[(size_t)row * 1024 + c] = f2bf(yv[i] * iy);
  }
}

// ---------------- uv (bf16, pre-scaled) -> justnorm row 8192 -> res = u*silu(v) in-place ----------------
__global__ __launch_bounds__(256) void uvres_kernel(u16* __restrict__ uv){
  const int row = blockIdx.x, tid = threadIdx.x;
  u16* p = uv + (size_t)row * 8192;
  float uvv[32]; float ss = 0.0f;
  const u16x8* su = (const u16x8*)(p + tid * 16);
  const u16x8* sv = (const u16x8*)(p + 4096 + tid * 16);
  u16x8 a0 = su[0], a1 = su[1], b0 = sv[0], b1 = sv[1];
  #pragma unroll
  for (int j = 0; j < 8; ++j){
    uvv[j]      = bf2f(a0[j]); uvv[8 + j]  = bf2f(a1[j]);
    uvv[16 + j] = bf2f(b0[j]); uvv[24 + j] = bf2f(b1[j]);
  }
  #pragma unroll
  for (int j = 0; j < 32; ++j) ss += uvv[j] * uvv[j];
  __shared__ float red[4];
  ss = waveSum(ss);
  if ((tid & 63) == 0) red[tid >> 6] = ss;
  __syncthreads();
  const float tot = red[0] + red[1] + red[2] + red[3];
  const float inv = 1.0f / sqrtf(tot);
  #pragma unroll
  for (int j = 0; j < 16; ++j){
    const float un = uvv[j] * inv;
    const float vn = uvv[16 + j] * inv;
    const float sil = vn / (1.0f + expf(-vn));
    p[tid * 16 + j] = f2bf(un * sil);
  }
}

// ---------------- final: justnorm(justnorm(x2) + lr2*(justnorm(t2)-justnorm(x2))) ----------------
// x2 read as bf16 (same buffer Wu consumed); t2 fp32.
__global__ __launch_bounds__(256) void final_kernel(const u16* __restrict__ x2,
                                                    const float* __restrict__ t2,
                                                    const float* __restrict__ alpha,
                                                    float* __restrict__ out){
  const int row = blockIdx.x, tid = threadIdx.x, lane = tid & 63, wv = tid >> 6;
  const u16* a = x2 + (size_t)row * 1024;
  const float* b = t2 + (size_t)row * 1024;
  float av[4], bv[4]; float sa = 0.0f, sb = 0.0f;
  #pragma unroll
  for (int i = 0; i < 4; ++i){
    av[i] = bf2f(a[tid + i * 256]); sa += av[i] * av[i];
    bv[i] = b[tid + i * 256]; sb += bv[i] * bv[i];
  }
  __shared__ float red[8];
  sa = waveSum(sa); sb = waveSum(sb);
  if (lane == 0){ red[wv] = sa; red[4 + wv] = sb; }
  __syncthreads();
  sa = red[0] + red[1] + red[2] + red[3];
  sb = red[4] + red[5] + red[6] + red[7];
  const float ia = 1.0f / sqrtf(sa), ib = 1.0f / sqrtf(sb);
  float yv[4]; float sy = 0.0f;
  #pragma unroll
  for (int i = 0; i < 4; ++i){
    const int c = tid + i * 256;
    const float lr = fabsf(alpha[c] * 0.05f);
    const float an = av[i] * ia, bn = bv[i] * ib;
    yv[i] = an + lr * (bn - an);
    sy += yv[i] * yv[i];
  }
  sy = waveSum(sy);
  __syncthreads();
  if (lane == 0) red[wv] = sy;
  __syncthreads();
  sy = red[0] + red[1] + red[2] + red[3];
  const float iy = 1.0f / sqrtf(sy);
  #pragma unroll
  for (int i = 0; i < 4; ++i)
    out[(size_t)row * 1024 + tid + i * 256] = yv[i] * iy;
}

extern "C" void kernel_launch(void* const* d_in, const int* in_sizes, int n_in,
                              void* d_out, int out_size, void* d_ws, size_t ws_size,
                              hipStream_t stream) {
  const float* x          = (const float*)d_in[0];
  const float* Wqkv       = (const float*)d_in[1];
  const float* sqk        = (const float*)d_in[2];
  const float* W_O        = (const float*)d_in[3];
  const float* attn_alpha = (const float*)d_in[4];
  const float* Wu_w       = (const float*)d_in[5];
  const float* Wu_b       = (const float*)d_in[6];
  const float* suv        = (const float*)d_in[7];
  const float* Wv_w       = (const float*)d_in[8];
  const float* Wv_b       = (const float*)d_in[9];
  const float* mlp_alpha  = (const float*)d_in[10];
  float* out = (float*)d_out;

  char* ws = (char*)d_ws;
  // workspace layout (128 MiB total, aliased):
  //   wbuf 0-16M:  Wqkv bf16 [0,6M) | W_O bf16 [6M,8M) | rope tab [8M,8.5M); later Wu bf16 (full 16M)
  //   abuf 16-24M: x bf16 -> ob_norm -> x2b (read by Wu GEMM and final)
  //   24-40M:      qkb Q|K [dead after attn] -> tbuf fp32
  //   40-48M:      Wv bf16 (live until Wv GEMM; nothing else touches this range)
  //   48-64M:      aout fp32 (attn out)
  //   64-128M:     vtb V^T [dead after attn] -> uvb (Wu out)
  u16*   wbuf  = (u16*)(ws);
  u16*   wob   = (u16*)(ws + 6291456);
  float2* rtab = (float2*)(ws + 8388608);
  u16*   abuf  = (u16*)(ws + 16777216);
  u16*   qkb   = (u16*)(ws + 25165824);
  float* tbuf  = (float*)(ws + 25165824);
  u16*   wvb   = (u16*)(ws + 41943040);
  float* aout  = (float*)(ws + 50331648);
  u16*   uvb   = (u16*)(ws + 67108864);
  u16*   vtb   = (u16*)(ws + 67108864);

  const int M = Bc * Tc;  // 4096

  // 0. batched converts: x -> abuf, Wqkv -> wbuf, W_O -> wob, Wv -> wvb
  cvt_all<<<dim3(2048), dim3(256), 0, stream>>>(
      x, Wqkv, W_O, Wv_w, abuf, wbuf, wob, wvb);
  rope_table<<<dim3(Tc * 32 / 256), 256, 0, stream>>>(rtab);

  // 1. qkv = x @ Wqkv^T  -> Q|K packed [bh][t][128] + V^T [bh][d][VTS]
  gemm_bt<1><<<dim3(3072 / 128, M / 128), 256, 0, stream>>>(
      abuf, DMc, wbuf, nullptr, qkb, vtb, nullptr, nullptr, 0.0f, M, 3072, DMc);

  // 2. RoPE/justnorm/sqk on Q,K
  rope_norm<<<dim3(Bc * Hc * Tc / 4), 256, 0, stream>>>(qkb, sqk, rtab);

  // 3. causal flash attention -> aout (b,t,h*64+d) fp32
  attn_kernel<<<dim3(Tc / 128, Bc * Hc), 256, 0, stream>>>(qkb, vtb, aout);

  // 4. justnorm rows -> bf16, then t = . @ W_O^T (fp32)  [64-tile GEMM, BK=128]
  rownorm1024<<<dim3(M), 256, 0, stream>>>(aout, abuf);
  gemm64_bt<<<dim3(DMc / 64, M / 64), 256, 0, stream>>>(
      abuf, DMc, wob, DMc, tbuf, nullptr, M, DMc, DMc);

  // 5. x2 residual mix -> abuf (bf16 only; also read by final_kernel)
  x2_kernel<<<dim3(M), 256, 0, stream>>>(x, tbuf, attn_alpha, abuf);

  // 6. uv = (x2 @ Wu^T + b) * suv * 32  (bf16)  [256² 8-phase pipeline]
  //    Wu bf16 into wbuf (Wqkv / W_O / rope table all dead by now)
  cvt_f32_bf16<<<dim3(4096), dim3(256), 0, stream>>>(Wu_w, wbuf, 8192 * DMc / 4);
  gemm256_bt<<<dim3(8192 / 256, M / 256), 512, 0, stream>>>(
      abuf, DMc, wbuf, DMc, uvb, Wu_b, suv, 32.0f, M, 8192, DMc);

  // 7. row-norm 8192 + u*silu(v) in-place into u half
  uvres_kernel<<<dim3(M), 256, 0, stream>>>(uvb);

  // 8. t2 = res @ Wv^T + b (fp32)  [64-tile GEMM, BK=128]
  gemm64_bt<<<dim3(DMc / 64, M / 64), 256, 0, stream>>>(
      uvb, 8192, wvb, 4096, tbuf, Wv_b, M, DMc, 4096);

  // 9. final residual mix -> d_out (x2 from abuf bf16)
  final_kernel<<<dim3(M), 256, 0, stream>>>(abuf, tbuf, mlp_alpha, out);
}

// Round 16
// 304.746 us; speedup vs baseline: 1.0256x; 1.0079x over previous
//
#include <hip/hip_runtime.h>
#include <cstdint>
#include <cstddef>

#define DEVI __device__ __forceinline__

typedef __attribute__((ext_vector_type(8))) short s16x8;
typedef __attribute__((ext_vector_type(8))) unsigned short u16x8;
typedef __attribute__((ext_vector_type(4))) float f32x4;
typedef unsigned short u16;

static constexpr int Bc = 2, Tc = 2048, Hc = 16, DMc = 1024;
static constexpr int VTS = 2064;  // V^T row stride in u16 (4128B: non-pow2, 16B-aligned)

DEVI float bf2f(u16 u){ unsigned int x = ((unsigned int)u) << 16; return __builtin_bit_cast(float, x); }
DEVI u16 f2bf(float f){
  unsigned int u = __builtin_bit_cast(unsigned int, f);
  u += 0x7FFFu + ((u >> 16) & 1u);
  return (u16)(u >> 16);
}

DEVI float waveSum(float v){
  #pragma unroll
  for (int m = 1; m < 64; m <<= 1) v += __shfl_xor(v, m);
  return v;
}

DEVI void gload16(const void* g, void* l){
  __builtin_amdgcn_global_load_lds((const __attribute__((address_space(1))) void*)g,
                                   (__attribute__((address_space(3))) void*)l, 16, 0, 0);
}

// ---------------- batched fp32 -> bf16: x | Wqkv | W_O | Wv | Wu in one launch ----------------
// segments (float4 units): x 1048576 | wqkv 786432 | wo 262144 | wv 1048576 | wu 2097152
__global__ __launch_bounds__(256) void cvt_all(
    const float* __restrict__ x,  const float* __restrict__ wqkv,
    const float* __restrict__ wo, const float* __restrict__ wv,
    const float* __restrict__ wu,
    u16* __restrict__ xb, u16* __restrict__ wqkvb,
    u16* __restrict__ wob, u16* __restrict__ wvb, u16* __restrict__ wub)
{
  const int total = 5242880;
  int i = blockIdx.x * blockDim.x + threadIdx.x;
  const int stride = gridDim.x * blockDim.x;
  for (int idx = i; idx < total; idx += stride){
    const float4* s; ushort4* d; int l;
    if (idx < 1048576){      s = (const float4*)x;    d = (ushort4*)xb;    l = idx; }
    else if (idx < 1835008){ s = (const float4*)wqkv; d = (ushort4*)wqkvb; l = idx - 1048576; }
    else if (idx < 2097152){ s = (const float4*)wo;   d = (ushort4*)wob;   l = idx - 1835008; }
    else if (idx < 3145728){ s = (const float4*)wv;   d = (ushort4*)wvb;   l = idx - 2097152; }
    else {                   s = (const float4*)wu;   d = (ushort4*)wub;   l = idx - 3145728; }
    float4 v = s[l];
    ushort4 o;
    o.x = f2bf(v.x); o.y = f2bf(v.y); o.z = f2bf(v.z); o.w = f2bf(v.w);
    d[l] = o;
  }
}

// ---------------- GEMM 256x256, BK=64, 8-phase counted-vmcnt pipeline ----------------
__global__ __launch_bounds__(512, 1) void gemm256_bt(
    const u16* __restrict__ A, int lda, const u16* __restrict__ W, int ldw,
    u16* __restrict__ outB, const float* __restrict__ bias,
    const float* __restrict__ scale, float smul,
    int M, int N, int K)
{
  __shared__ u16 lds8[65536];   // 128 KiB: A slots [0,32768), B slots [32768,65536)
  const int tid = threadIdx.x, lane = tid & 63, wave = tid >> 6;
  const int wm = wave >> 2, wn = wave & 3;
  const int g = lane >> 4, cl = lane & 15;
  // n-chunked XCD swizzle (gridDim.x % 8 == 0)
  const int F = blockIdx.y * gridDim.x + blockIdx.x;
  const int xcd = F & 7, i0 = F >> 3;
  const int NCH = gridDim.x >> 3;
  const int n0 = (xcd * NCH + i0 % NCH) * 256;
  const int m0 = (i0 / NCH) * 256;

  const int nt = K >> 6;         // K-tiles
  const int iters = nt >> 1;     // 2 K-tiles per iteration
  const int wuni = tid & ~63;

  f32x4 acc[8][4] = {};

  auto stageA = [&](int h, int t){
    char* dst = (char*)(lds8 + (size_t)(2 * (t & 1) + h) * 8192);
    const int k0 = t << 6;
    #pragma unroll
    for (int j = 0; j < 2; ++j){
      const int idx = j * 512 + tid;            // 0..1023: row=idx>>3, blk=idx&7
      const int row = idx >> 3;
      const int sb = ((idx & 7) ^ (row & 7)) << 3;
      gload16(A + (size_t)(m0 + h * 128 + row) * lda + k0 + sb,
              dst + ((j * 512 + wuni) << 4));
    }
  };
  auto stageB = [&](int h, int t){
    char* dst = (char*)(lds8 + 32768 + (size_t)(2 * (t & 1) + h) * 8192);
    const int k0 = t << 6;
    #pragma unroll
    for (int j = 0; j < 2; ++j){
      const int idx = j * 512 + tid;
      const int row = idx >> 3;
      const int sb = ((idx & 7) ^ (row & 7)) << 3;
      gload16(W + (size_t)(n0 + h * 128 + row) * ldw + k0 + sb,
              dst + ((j * 512 + wuni) << 4));
    }
  };

  // prologue: B(0), A(0), B(1) = 12 gloads
  stageB(0, 0); stageB(1, 0); stageA(0, 0); stageA(1, 0); stageB(0, 1); stageB(1, 1);

  s16x8 bF[4][2];
  for (int v = 0; v < iters; ++v){
    const bool lastIt = (v == iters - 1);
    #pragma unroll
    for (int p = 0; p < 8; ++p){
      const int tt = p >> 2, q = p & 3;
      const int t = 2 * v + tt;
      // stage schedule (slot legality: re-stage only after last read's barrier)
      if (p == 0)      stageA(0, 2 * v + 1);
      else if (p == 1) stageA(1, 2 * v + 1);
      else if (p == 2){ if (2 * v + 2 < nt) stageB(0, 2 * v + 2); }
      else if (p == 3){ if (2 * v + 2 < nt) stageB(1, 2 * v + 2); }
      else if (p == 4){ if (2 * v + 2 < nt) stageA(0, 2 * v + 2); }
      else if (p == 5){ if (2 * v + 2 < nt) stageA(1, 2 * v + 2); }
      else if (p == 6){ if (2 * v + 3 < nt) stageB(0, 2 * v + 3); }
      else            { if (2 * v + 3 < nt) stageB(1, 2 * v + 3); }

      if (p == 0) asm volatile("s_waitcnt vmcnt(6)" ::: "memory");
      if (p == 4){
        if (lastIt) asm volatile("s_waitcnt vmcnt(0)" ::: "memory");
        else        asm volatile("s_waitcnt vmcnt(6)" ::: "memory");
      }

      // ds_read register subtile
      const int abase = (2 * (t & 1) + wm) * 8192;
      s16x8 aF[2][2];
      #pragma unroll
      for (int i2 = 0; i2 < 2; ++i2){
        const int r = (2 * q + i2) * 16 + cl;
        #pragma unroll
        for (int kk = 0; kk < 2; ++kk)
          aF[i2][kk] = *(const s16x8*)&lds8[abase + r * 64 + (((kk * 4 + g) ^ (r & 7)) << 3)];
      }
      if (q == 0){
        const int bbase = 32768 + (2 * (t & 1) + (wn >> 1)) * 8192;
        #pragma unroll
        for (int j = 0; j < 4; ++j){
          const int rb2 = (wn & 1) * 64 + j * 16 + cl;
          #pragma unroll
          for (int kk = 0; kk < 2; ++kk)
            bF[j][kk] = *(const s16x8*)&lds8[bbase + rb2 * 64 + (((kk * 4 + g) ^ (rb2 & 7)) << 3)];
        }
      }

      asm volatile("s_barrier" ::: "memory");
      __builtin_amdgcn_s_setprio(1);
      #pragma unroll
      for (int i2 = 0; i2 < 2; ++i2)
        #pragma unroll
        for (int j = 0; j < 4; ++j)
          #pragma unroll
          for (int kk = 0; kk < 2; ++kk)
            acc[2 * q + i2][j] = __builtin_amdgcn_mfma_f32_16x16x32_bf16(
                aF[i2][kk], bF[j][kk], acc[2 * q + i2][j], 0, 0, 0);
      __builtin_amdgcn_s_setprio(0);
      asm volatile("s_barrier" ::: "memory");
    }
  }

  // epilogue
  const int rb = m0 + wm * 128 + (g << 2);
  const int cb = n0 + wn * 64 + cl;
  #pragma unroll
  for (int i = 0; i < 8; ++i){
    #pragma unroll
    for (int j = 0; j < 4; ++j){
      const int col = cb + j * 16;
      const float sc = scale[col] * smul;
      const float bi = bias[col];
      #pragma unroll
      for (int r = 0; r < 4; ++r){
        const int row = rb + i * 16 + r;
        outB[(size_t)row * N + col] = f2bf((acc[i][j][r] + bi) * sc);
      }
    }
  }
}

// ---------------- GEMM 128x128, BK=64, XOR-swizzled LDS (conflict-free) ----------------
// EPI 0: fp32 out (+ optional bias)
// EPI 1: bf16 out: Q,K -> qk[bh][t][128]; V -> transposed vt[bh][d][VTS]
template<int EPI>
__global__ __launch_bounds__(256) void gemm_bt(
    const u16* __restrict__ A, int lda, const u16* __restrict__ W,
    float* __restrict__ outF, u16* __restrict__ outB, u16* __restrict__ outB2,
    const float* __restrict__ bias, const float* __restrict__ scale, float smul,
    int M, int N, int K)
{
  __shared__ u16 lA[128 * 64];
  __shared__ u16 lB[128 * 64];
  const int tid = threadIdx.x, lane = tid & 63;
  const int wave = tid >> 6, wm = wave >> 1, wn = wave & 1;
  const int g = lane >> 4, cl = lane & 15;
  // n-chunked XCD swizzle (requires gridDim.x % 8 == 0; bijective)
  const int F = blockIdx.y * gridDim.x + blockIdx.x;
  const int xcd = F & 7, i0 = F >> 3;
  const int NCH = gridDim.x >> 3;
  const int n0 = (xcd * NCH + i0 % NCH) * 128;
  const int m0 = (i0 / NCH) * 128;
  f32x4 acc[4][4] = {};
  const int kT = K >> 6;
  char* lAc = (char*)lA;
  char* lBc = (char*)lB;
  const int wuni = (tid & ~63);

  for (int kt = 0; kt < kT; ++kt){
    const int k0 = kt << 6;
    __syncthreads();
    #pragma unroll
    for (int j = 0; j < 4; ++j){
      const int idx = j * 256 + tid;            // 0..1023: row=idx>>3, blk=idx&7
      const int row = idx >> 3;
      const int sb = ((idx & 7) ^ (row & 7)) << 3;  // pre-swizzled source col-block
      gload16(A + (size_t)(m0 + row) * lda + k0 + sb,
              lAc + ((j * 256 + wuni) << 4));
    }
    #pragma unroll
    for (int j = 0; j < 4; ++j){
      const int idx = j * 256 + tid;
      const int row = idx >> 3;
      const int sb = ((idx & 7) ^ (row & 7)) << 3;
      gload16(W + (size_t)(n0 + row) * K + k0 + sb,
              lBc + ((j * 256 + wuni) << 4));
    }
    __syncthreads();

    #pragma unroll
    for (int kk = 0; kk < 2; ++kk){
      s16x8 aF[4], bF[4];
      #pragma unroll
      for (int i = 0; i < 4; ++i){
        const int ra = wm * 64 + i * 16 + cl;
        aF[i] = *(const s16x8*)&lA[ra * 64 + (((kk * 4 + g) ^ (ra & 7)) << 3)];
      }
      #pragma unroll
      for (int j = 0; j < 4; ++j){
        const int rbr = wn * 64 + j * 16 + cl;
        bF[j] = *(const s16x8*)&lB[rbr * 64 + (((kk * 4 + g) ^ (rbr & 7)) << 3)];
      }
      #pragma unroll
      for (int i = 0; i < 4; ++i)
        #pragma unroll
        for (int j = 0; j < 4; ++j)
          acc[i][j] = __builtin_amdgcn_mfma_f32_16x16x32_bf16(aF[i], bF[j], acc[i][j], 0, 0, 0);
    }
  }

  const int rb = m0 + wm * 64 + (g << 2);
  const int cb = n0 + wn * 64 + cl;
  #pragma unroll
  for (int i = 0; i < 4; ++i){
    #pragma unroll
    for (int j = 0; j < 4; ++j){
      #pragma unroll
      for (int r = 0; r < 4; ++r){
        const int row = rb + i * 16 + r;
        const int col = cb + j * 16;
        float v = acc[i][j][r];
        if (EPI == 0){
          if (bias) v += bias[col];
          outF[(size_t)row * N + col] = v;
        } else if (EPI == 1){
          const int b = row >> 11;           // T = 2048
          const int t = row & (Tc - 1);
          const int h = col / 192;
          const int e = col - h * 192;
          const int bh = b * Hc + h;
          if (e < 128){
            outB[((size_t)bh * Tc + t) * 128 + e] = f2bf(v);         // Q|K packed
          } else {
            outB2[((size_t)bh * 64 + (e - 128)) * VTS + t] = f2bf(v); // V^T [d][VTS]
          }
        } else {
          v = (v + bias[col]) * (scale[col] * smul);
          outB[(size_t)row * N + col] = f2bf(v);
        }
      }
    }
  }
}

// ---------------- GEMM 64x64, BK=128, XOR-swizzled LDS (conflict-free) ----------------
__global__ __launch_bounds__(256) void gemm64_bt(
    const u16* __restrict__ A, int lda, const u16* __restrict__ W, int ldw,
    float* __restrict__ outF, const float* __restrict__ bias,
    int M, int N, int K)
{
  __shared__ u16 lA[64 * 128];
  __shared__ u16 lB[64 * 128];
  const int tid = threadIdx.x, lane = tid & 63;
  const int wave = tid >> 6, wm = wave >> 1, wn = wave & 1;
  const int g = lane >> 4, cl = lane & 15;
  // XCD-chunked bijective swizzle (nwg % 8 == 0)
  const int nwg = gridDim.x * gridDim.y;
  int flat = blockIdx.y * gridDim.x + blockIdx.x;
  flat = (flat & 7) * (nwg >> 3) + (flat >> 3);
  const int n0 = (flat % gridDim.x) * 64;
  const int m0 = (flat / gridDim.x) * 64;
  f32x4 acc[2][2] = {};
  const int kT = K >> 7;
  const int wuni = tid & ~63;

  for (int kt = 0; kt < kT; ++kt){
    const int k0 = kt << 7;
    __syncthreads();
    #pragma unroll
    for (int it = 0; it < 4; ++it){
      const int idx = it * 256 + tid;        // 0..1023: row=idx>>4, blk=idx&15 (16x 16B/row)
      const int row = idx >> 4, blk = idx & 15;
      const int sb = ((blk & 8) | ((blk & 7) ^ (row & 7))) << 3;  // swizzle within 128B halves
      gload16(A + (size_t)(m0 + row) * lda + k0 + sb,
              (char*)lA + ((it * 256 + wuni) << 4));
      gload16(W + (size_t)(n0 + row) * ldw + k0 + sb,
              (char*)lB + ((it * 256 + wuni) << 4));
    }
    __syncthreads();

    #pragma unroll
    for (int kk = 0; kk < 4; ++kk){
      s16x8 aF[2], bF[2];
      #pragma unroll
      for (int i = 0; i < 2; ++i){
        const int ra = wm * 32 + i * 16 + cl;
        const int ba = kk * 4 + g;
        const int sa = ((ba & 8) | ((ba & 7) ^ (ra & 7))) << 3;
        aF[i] = *(const s16x8*)&lA[ra * 128 + sa];
        const int rbr = wn * 32 + i * 16 + cl;
        const int sbw = ((ba & 8) | ((ba & 7) ^ (rbr & 7))) << 3;
        bF[i] = *(const s16x8*)&lB[rbr * 128 + sbw];
      }
      #pragma unroll
      for (int i = 0; i < 2; ++i)
        #pragma unroll
        for (int j = 0; j < 2; ++j)
          acc[i][j] = __builtin_amdgcn_mfma_f32_16x16x32_bf16(aF[i], bF[j], acc[i][j], 0, 0, 0);
    }
  }

  const int rb = m0 + wm * 32 + (g << 2);
  const int cb = n0 + wn * 32 + cl;
  #pragma unroll
  for (int i = 0; i < 2; ++i){
    #pragma unroll
    for (int j = 0; j < 2; ++j){
      #pragma unroll
      for (int r = 0; r < 4; ++r){
        const int row = rb + i * 16 + r;
        const int col = cb + j * 16;
        float v = acc[i][j][r];
        if (bias) v += bias[col];
        outF[(size_t)row * N + col] = v;
      }
    }
  }
}

// ---------------- RoPE cos/sin table: tab[t][fi] = (cos, sin) ----------------
__global__ __launch_bounds__(256) void rope_table(float2* __restrict__ tab){
  const int i = blockIdx.x * 256 + threadIdx.x;   // 65536 = 2048*32
  const int t = i >> 5, fi = i & 31;
  const float invf = powf(10000.0f, -(float)fi / 32.0f);
  float sn, cs;
  sincosf((float)t * invf, &sn, &cs);
  tab[i] = make_float2(cs, sn);
}

// ---------------- RoPE + justnorm + sqk on Q,K in-place (qk layout [bh][t][128], bf16) ----------------
__global__ __launch_bounds__(256) void rope_norm(u16* __restrict__ qk,
                                                 const float* __restrict__ sqk,
                                                 const float2* __restrict__ tab){
  const int lane = threadIdx.x & 63;
  const int idx = blockIdx.x * 4 + (threadIdx.x >> 6);  // row over B*H*T
  const int t = idx & (Tc - 1);
  const int h = (idx >> 11) & (Hc - 1);
  u16* row = qk + (size_t)idx * 128;
  float q = bf2f(row[lane]), k = bf2f(row[64 + lane]);
  const int fi = lane & 31;
  const float2 cssn = tab[t * 32 + fi];
  const float cs = cssn.x, sn = cssn.y;
  float qo = __shfl_xor(q, 32), ko = __shfl_xor(k, 32);
  float rq = (lane < 32) ? -qo : qo;
  float rk = (lane < 32) ? -ko : ko;
  float qn = q * cs + rq * sn;
  float kn = k * cs + rk * sn;
  float sq = waveSum(qn * qn), sk = waveSum(kn * kn);
  float scl = sqk[h * 64 + lane];
  row[lane]      = f2bf(qn / sqrtf(sq) * scl);
  row[64 + lane] = f2bf(kn / sqrtf(sk) * scl);
}

// ---------------- causal flash attention ----------------
// Block = 4 waves = 64 q rows per chunk; complementary chunk pair (i, 31-i).
// NO-MAX softmax (|scores| <= 1/32).  KV in double-buffered XOR-swizzled LDS.
// Counted-vmcnt pipeline: raw s_barriers, vmcnt(4) keeps next-tile prefetch in flight.
__global__ __launch_bounds__(256) void attn_kernel(const u16* __restrict__ qk,
                                                   const u16* __restrict__ vt,
                                                   float* __restrict__ o){
  __shared__ u16 Kt[2][4096];   // [64 keys][64 dims], XOR-swizzled
  __shared__ u16 Vt[2][4096];   // [64 dims][64 keys], same swizzle
  __shared__ u16 Pt[4][1024];   // per-wave P tile [16 q][64 k], swizzled

  const int tid = threadIdx.x, lane = tid & 63, wave = tid >> 6;
  const int wuni = tid & ~63;
  // bh-clustered XCD remap (512 blocks: xcd = F&7 owns bh in [4*xcd, 4*xcd+4))
  const int F = (int)(blockIdx.y * gridDim.x + blockIdx.x);
  const int xcd = F & 7, ii = F >> 3;
  const int bh = xcd * 4 + (ii & 3);
  const int pr = ii >> 2;                  // pair-chunk index 0..15
  const int g = lane >> 4, cl = lane & 15;
  const u16* qkb = qk + (size_t)bh * Tc * 128;
  const u16* vtb = vt + (size_t)bh * 64 * VTS;
  const int b = bh / Hc, h = bh % Hc;

  auto stage = [&](int sel, int kb){
    #pragma unroll
    for (int it = 0; it < 2; ++it){
      const int idx = it * 256 + tid;        // 0..511 : row=idx>>3, blk=idx&7
      const int row = idx >> 3, blk = idx & 7;
      const int sb = (blk ^ (row & 7)) << 3;
      gload16(qkb + (size_t)(kb + row) * 128 + 64 + sb,
              (char*)Kt[sel] + ((it * 256 + wuni) << 4));
      gload16(vtb + (size_t)row * VTS + kb + sb,
              (char*)Vt[sel] + ((it * 256 + wuni) << 4));
    }
  };

  #pragma unroll 1
  for (int half = 0; half < 2; ++half){
    const int cq = (half == 0) ? pr : 31 - pr;
    const int q0b = cq * 64;
    const int qw = q0b + wave * 16;          // this wave's first q row
    const int nsteps = cq + 1;

    s16x8 qF[2];
    {
      const u16* qrow = qkb + (size_t)(qw + cl) * 128 + (g << 3);
      qF[0] = *(const s16x8*)qrow;
      qF[1] = *(const s16x8*)(qrow + 32);
    }
    f32x4 oF[4] = {};
    float lsum[4] = {0.0f, 0.0f, 0.0f, 0.0f};

    auto compute = [&](int sel, int kb){
      const u16* Kl = Kt[sel];
      const u16* Vl = Vt[sel];
      u16* pw = Pt[wave];
      f32x4 sF[4] = {};
      #pragma unroll
      for (int c16 = 0; c16 < 4; ++c16){
        const int kr = c16 * 16 + cl;
        s16x8 k0 = *(const s16x8*)&Kl[kr * 64 + (((g)     ^ (cl & 7)) << 3)];
        s16x8 k1 = *(const s16x8*)&Kl[kr * 64 + (((4 + g) ^ (cl & 7)) << 3)];
        sF[c16] = __builtin_amdgcn_mfma_f32_16x16x32_bf16(qF[0], k0, sF[c16], 0, 0, 0);
        sF[c16] = __builtin_amdgcn_mfma_f32_16x16x32_bf16(qF[1], k1, sF[c16], 0, 0, 0);
      }
      const float c = 46.16624f;  // 32 * log2(e)
      #pragma unroll
      for (int r = 0; r < 4; ++r){
        const int qg = qw + g * 4 + r;
        const float p0 = (kb + cl      > qg) ? 0.0f : exp2f(sF[0][r] * c);
        const float p1 = (kb + 16 + cl > qg) ? 0.0f : exp2f(sF[1][r] * c);
        const float p2 = (kb + 32 + cl > qg) ? 0.0f : exp2f(sF[2][r] * c);
        const float p3 = (kb + 48 + cl > qg) ? 0.0f : exp2f(sF[3][r] * c);
        lsum[r] += (p0 + p1) + (p2 + p3);
        const int rp = g * 4 + r;
        const int rsw = (rp & 7);
        pw[rp * 64 + ((((cl >> 3)    ) ^ rsw) << 3) + (cl & 7)] = f2bf(p0);
        pw[rp * 64 + ((((cl >> 3) + 2) ^ rsw) << 3) + (cl & 7)] = f2bf(p1);
        pw[rp * 64 + ((((cl >> 3) + 4) ^ rsw) << 3) + (cl & 7)] = f2bf(p2);
        pw[rp * 64 + ((((cl >> 3) + 6) ^ rsw) << 3) + (cl & 7)] = f2bf(p3);
      }
      #pragma unroll
      for (int ksub = 0; ksub < 2; ++ksub){
        s16x8 pF = *(const s16x8*)&pw[cl * 64 + (((ksub * 4 + g) ^ (cl & 7)) << 3)];
        #pragma unroll
        for (int d0 = 0; d0 < 4; ++d0){
          s16x8 vF = *(const s16x8*)&Vl[(d0 * 16 + cl) * 64 + (((ksub * 4 + g) ^ (cl & 7)) << 3)];
          oF[d0] = __builtin_amdgcn_mfma_f32_16x16x32_bf16(pF, vF, oF[d0], 0, 0, 0);
        }
      }
    };

    // counted-vmcnt pipeline: batch kt waits happen one full step after issue
    stage(0, 0);
    for (int kt = 0; kt < nsteps; ++kt){
      const int sel = kt & 1;
      const int kb = kt * 64;
      if (kt + 1 < nsteps){
        stage(sel ^ 1, (kt + 1) * 64);                    // 4 gloads (batch kt+1)
        asm volatile("s_waitcnt vmcnt(4)" ::: "memory");  // batch kt landed; kt+1 in flight
      } else {
        asm volatile("s_waitcnt vmcnt(0)" ::: "memory");  // last tile: full drain
      }
      asm volatile("s_barrier" ::: "memory");             // all waves' batch kt visible
      compute(sel, kb);
      asm volatile("s_barrier" ::: "memory");             // all reads of buf[sel] done
    }

    float invl[4];
    #pragma unroll
    for (int r = 0; r < 4; ++r){
      float l = lsum[r];
      l += __shfl_xor(l, 1);
      l += __shfl_xor(l, 2);
      l += __shfl_xor(l, 4);
      l += __shfl_xor(l, 8);
      invl[r] = 1.0f / l;
    }
    #pragma unroll
    for (int d0 = 0; d0 < 4; ++d0){
      #pragma unroll
      for (int r = 0; r < 4; ++r){
        const int qg = qw + g * 4 + r;
        o[((size_t)(b * Tc + qg)) * DMc + h * 64 + d0 * 16 + cl] = oF[d0][r] * invl[r];
      }
    }
  }
}

// ---------------- row-wise justnorm of 1024-row -> bf16 ----------------
__global__ __launch_bounds__(256) void rownorm1024(const float* __restrict__ in,
                                                   u16* __restrict__ out){
  const int row = blockIdx.x, tid = threadIdx.x;
  const float* r = in + (size_t)row * 1024;
  float v[4]; float ss = 0.0f;
  #pragma unroll
  for (int i = 0; i < 4; ++i){ v[i] = r[tid + i * 256]; ss += v[i] * v[i]; }
  __shared__ float red[4];
  ss = waveSum(ss);
  if ((tid & 63) == 0) red[tid >> 6] = ss;
  __syncthreads();
  const float tot = red[0] + red[1] + red[2] + red[3];
  const float inv = 1.0f / sqrtf(tot);
  #pragma unroll
  for (int i = 0; i < 4; ++i) out[(size_t)row * 1024 + tid + i * 256] = f2bf(v[i] * inv);
}

// ---------------- x2 = justnorm(justnorm(x) + lr*(justnorm(t)-justnorm(x))) -> bf16 only ----------------
__global__ __launch_bounds__(256) void x2_kernel(const float* __restrict__ x,
                                                 const float* __restrict__ t,
                                                 const float* __restrict__ alpha,
                                                 u16* __restrict__ x2b){
  const int row = blockIdx.x, tid = threadIdx.x, lane = tid & 63, wv = tid >> 6;
  const float* xr = x + (size_t)row * 1024;
  const float* tr = t + (size_t)row * 1024;
  float xv[4], tv[4]; float sx = 0.0f, st = 0.0f;
  #pragma unroll
  for (int i = 0; i < 4; ++i){
    xv[i] = xr[tid + i * 256]; sx += xv[i] * xv[i];
    tv[i] = tr[tid + i * 256]; st += tv[i] * tv[i];
  }
  __shared__ float red[8];
  sx = waveSum(sx); st = waveSum(st);
  if (lane == 0){ red[wv] = sx; red[4 + wv] = st; }
  __syncthreads();
  sx = red[0] + red[1] + red[2] + red[3];
  st = red[4] + red[5] + red[6] + red[7];
  const float ix = 1.0f / sqrtf(sx), it = 1.0f / sqrtf(st);
  float yv[4]; float sy = 0.0f;
  #pragma unroll
  for (int i = 0; i < 4; ++i){
    const int c = tid + i * 256;
    const float lr = fabsf(alpha[c] * 1.6f);  // 0.05 / C^-0.5 = 0.05*32
    const float a = xv[i] * ix, bn = tv[i] * it;
    yv[i] = a + lr * (bn - a);
    sy += yv[i] * yv[i];
  }
  sy = waveSum(sy);
  __syncthreads();
  if (lane == 0) red[wv] = sy;
  __syncthreads();
  sy = red[0] + red[1] + red[2] + red[3];
  const float iy = 1.0f / sqrtf(sy);
  #pragma unroll
  for (int i = 0; i < 4; ++i){
    const int c = tid + i * 256;
    x2b[(size_t)row * 1024 + c] = f2bf(yv[i] * iy);
  }
}

// ---------------- uv (bf16, pre-scaled) -> justnorm row 8192 -> res = u*silu(v) in-place ----------------
__global__ __launch_bounds__(256) void uvres_kernel(u16* __restrict__ uv){
  const int row = blockIdx.x, tid = threadIdx.x;
  u16* p = uv + (size_t)row * 8192;
  float uvv[32]; float ss = 0.0f;
  const u16x8* su = (const u16x8*)(p + tid * 16);
  const u16x8* sv = (const u16x8*)(p + 4096 + tid * 16);
  u16x8 a0 = su[0], a1 = su[1], b0 = sv[0], b1 = sv[1];
  #pragma unroll
  for (int j = 0; j < 8; ++j){
    uvv[j]      = bf2f(a0[j]); uvv[8 + j]  = bf2f(a1[j]);
    uvv[16 + j] = bf2f(b0[j]); uvv[24 + j] = bf2f(b1[j]);
  }
  #pragma unroll
  for (int j = 0; j < 32; ++j) ss += uvv[j] * uvv[j];
  __shared__ float red[4];
  ss = waveSum(ss);
  if ((tid & 63) == 0) red[tid >> 6] = ss;
  __syncthreads();
  const float tot = red[0] + red[1] + red[2] + red[3];
  const float inv = 1.0f / sqrtf(tot);
  #pragma unroll
  for (int j = 0; j < 16; ++j){
    const float un = uvv[j] * inv;
    const float vn = uvv[16 + j] * inv;
    const float sil = vn / (1.0f + expf(-vn));
    p[tid * 16 + j] = f2bf(un * sil);
  }
}

// ---------------- final: justnorm(justnorm(x2) + lr2*(justnorm(t2)-justnorm(x2))) ----------------
// x2 read as bf16 (same buffer Wu consumed); t2 fp32.
__global__ __launch_bounds__(256) void final_kernel(const u16* __restrict__ x2,
                                                    const float* __restrict__ t2,
                                                    const float* __restrict__ alpha,
                                                    float* __restrict__ out){
  const int row = blockIdx.x, tid = threadIdx.x, lane = tid & 63, wv = tid >> 6;
  const u16* a = x2 + (size_t)row * 1024;
  const float* b = t2 + (size_t)row * 1024;
  float av[4], bv[4]; float sa = 0.0f, sb = 0.0f;
  #pragma unroll
  for (int i = 0; i < 4; ++i){
    av[i] = bf2f(a[tid + i * 256]); sa += av[i] * av[i];
    bv[i] = b[tid + i * 256]; sb += bv[i] * bv[i];
  }
  __shared__ float red[8];
  sa = waveSum(sa); sb = waveSum(sb);
  if (lane == 0){ red[wv] = sa; red[4 + wv] = sb; }
  __syncthreads();
  sa = red[0] + red[1] + red[2] + red[3];
  sb = red[4] + red[5] + red[6] + red[7];
  const float ia = 1.0f / sqrtf(sa), ib = 1.0f / sqrtf(sb);
  float yv[4]; float sy = 0.0f;
  #pragma unroll
  for (int i = 0; i < 4; ++i){
    const int c = tid + i * 256;
    const float lr = fabsf(alpha[c] * 0.05f);
    const float an = av[i] * ia, bn = bv[i] * ib;
    yv[i] = an + lr * (bn - an);
    sy += yv[i] * yv[i];
  }
  sy = waveSum(sy);
  __syncthreads();
  if (lane == 0) red[wv] = sy;
  __syncthreads();
  sy = red[0] + red[1] + red[2] + red[3];
  const float iy = 1.0f / sqrtf(sy);
  #pragma unroll
  for (int i = 0; i < 4; ++i)
    out[(size_t)row * 1024 + tid + i * 256] = yv[i] * iy;
}

extern "C" void kernel_launch(void* const* d_in, const int* in_sizes, int n_in,
                              void* d_out, int out_size, void* d_ws, size_t ws_size,
                              hipStream_t stream) {
  const float* x          = (const float*)d_in[0];
  const float* Wqkv       = (const float*)d_in[1];
  const float* sqk        = (const float*)d_in[2];
  const float* W_O        = (const float*)d_in[3];
  const float* attn_alpha = (const float*)d_in[4];
  const float* Wu_w       = (const float*)d_in[5];
  const float* Wu_b       = (const float*)d_in[6];
  const float* suv        = (const float*)d_in[7];
  const float* Wv_w       = (const float*)d_in[8];
  const float* Wv_b       = (const float*)d_in[9];
  const float* mlp_alpha  = (const float*)d_in[10];
  float* out = (float*)d_out;

  char* ws = (char*)d_ws;
  // workspace layout (128 MiB total, aliased):
  //   0-16M:    Wqkv bf16 [0,6M) | W_O bf16 [6M,8M) | rope tab [8M,8.5M)   [all dead after step 4]
  //   16-24M:   abuf: x bf16 -> ob_norm -> x2b (read by Wu GEMM and final)
  //   24-40M:   qkb Q|K [dead after attn] -> tbuf fp32 (W_O out, Wv out)
  //   40-48M:   Wv bf16 (live until Wv GEMM; nothing else touches this range)
  //   48-112M:  aout fp32 (48-64, dead after rownorm) / vtb (64-72.5, dead after attn) -> uvb
  //   112-128M: Wu bf16 (written at step 0, read only by gemm256; nothing else touches)
  u16*   wbuf  = (u16*)(ws);
  u16*   wob   = (u16*)(ws + 6291456);
  float2* rtab = (float2*)(ws + 8388608);
  u16*   abuf  = (u16*)(ws + 16777216);
  u16*   qkb   = (u16*)(ws + 25165824);
  float* tbuf  = (float*)(ws + 25165824);
  u16*   wvb   = (u16*)(ws + 41943040);
  float* aout  = (float*)(ws + 50331648);
  u16*   uvb   = (u16*)(ws + 50331648);
  u16*   vtb   = (u16*)(ws + 67108864);
  u16*   wub   = (u16*)(ws + 117440512);

  const int M = Bc * Tc;  // 4096

  // 0. all fp32->bf16 converts in one launch + rope table
  cvt_all<<<dim3(4096), dim3(256), 0, stream>>>(
      x, Wqkv, W_O, Wv_w, Wu_w, abuf, wbuf, wob, wvb, wub);
  rope_table<<<dim3(Tc * 32 / 256), 256, 0, stream>>>(rtab);

  // 1. qkv = x @ Wqkv^T  -> Q|K packed [bh][t][128] + V^T [bh][d][VTS]
  gemm_bt<1><<<dim3(3072 / 128, M / 128), 256, 0, stream>>>(
      abuf, DMc, wbuf, nullptr, qkb, vtb, nullptr, nullptr, 0.0f, M, 3072, DMc);

  // 2. RoPE/justnorm/sqk on Q,K
  rope_norm<<<dim3(Bc * Hc * Tc / 4), 256, 0, stream>>>(qkb, sqk, rtab);

  // 3. causal flash attention -> aout (b,t,h*64+d) fp32
  attn_kernel<<<dim3(Tc / 128, Bc * Hc), 256, 0, stream>>>(qkb, vtb, aout);

  // 4. justnorm rows -> bf16, then t = . @ W_O^T (fp32)  [64-tile GEMM, BK=128]
  rownorm1024<<<dim3(M), 256, 0, stream>>>(aout, abuf);
  gemm64_bt<<<dim3(DMc / 64, M / 64), 256, 0, stream>>>(
      abuf, DMc, wob, DMc, tbuf, nullptr, M, DMc, DMc);

  // 5. x2 residual mix -> abuf (bf16 only; also read by final_kernel)
  x2_kernel<<<dim3(M), 256, 0, stream>>>(x, tbuf, attn_alpha, abuf);

  // 6. uv = (x2 @ Wu^T + b) * suv * 32  (bf16)  [256² 8-phase pipeline; W from wub]
  gemm256_bt<<<dim3(8192 / 256, M / 256), 512, 0, stream>>>(
      abuf, DMc, wub, DMc, uvb, Wu_b, suv, 32.0f, M, 8192, DMc);

  // 7. row-norm 8192 + u*silu(v) in-place into u half
  uvres_kernel<<<dim3(M), 256, 0, stream>>>(uvb);

  // 8. t2 = res @ Wv^T + b (fp32)  [64-tile GEMM, BK=128]
  gemm64_bt<<<dim3(DMc / 64, M / 64), 256, 0, stream>>>(
      uvb, 8192, wvb, 4096, tbuf, Wv_b, M, DMc, 4096);

  // 9. final residual mix -> d_out (x2 from abuf bf16)
  final_kernel<<<dim3(M), 256, 0, stream>>>(abuf, tbuf, mlp_alpha, out);
}